// Round 5
// baseline (13775.797 us; speedup 1.0000x reference)
//
#include <hip/hip_runtime.h>
#include <hip/hip_bf16.h>
#include <math.h>

// ---------- constants ----------
#define BB 4
#define FBINS 196
#define TT 1000
#define DM 512
#define HH 8
#define DEPTH 64
#define FFN 2048
#define LL 4
#define EDIM 128
#define BT (BB*TT)   // 4000

typedef __hip_bfloat16 bf16;

// ---------- private arena (avoids any dependence on ws_size) ----------
// Allocated at dlopen time (outside kernel_launch, before graph capture).
#define ARENA_BYTES 160000000ULL
static void* g_arena = nullptr;
__attribute__((constructor)) static void arena_init() {
    if (!g_arena) (void)hipMalloc(&g_arena, ARENA_BYTES);
}

__device__ __forceinline__ float gelu_f(float x) {
    return 0.5f * x * (1.0f + erff(x * 0.70710678118654752440f));
}

// ---------- dtype sniffer ----------
// If inputs are fp32 misdeclared as bf16, their low halves (odd u16s) are
// near-uniform bit patterns -> thousands of bf16-NaN patterns per 1M elems.
// Genuine finite bf16 weights -> zero. cnt==0  <=>  inputs are bf16.
__global__ __launch_bounds__(256) void sniff_k(const unsigned short* __restrict__ p,
                                               int n, int* __restrict__ cnt) {
    int i = blockIdx.x * 256 + threadIdx.x;
    int c = 0;
    for (; i < n; i += gridDim.x * 256) {
        unsigned short u = p[i];
        if ((unsigned short)(u & 0x7FFF) > (unsigned short)0x7F80) c++;
    }
    if (c) atomicAdd(cnt, c);
}

// ---------- convert all 26 inputs into packed fp32 params ----------
struct CvtArgs {
    const void* src[26];
    unsigned off[27];      // cumulative element offsets; off[26] = total
    const int* cnt;        // 0 -> inputs are bf16; >0 -> fp32
    float* dst;
};
__global__ __launch_bounds__(256) void cvt_all(CvtArgs a) {
    unsigned i = blockIdx.x * 256 + threadIdx.x;
    if (i >= a.off[26]) return;
    bool isb = (*a.cnt == 0);
    int w = 0;
    while (i >= a.off[w + 1]) w++;
    unsigned j = i - a.off[w];
    float v = isb ? __bfloat162float(((const bf16*)a.src[w])[j])
                  : ((const float*)a.src[w])[j];
    a.dst[i] = v;
}

// ---------- output store (dtype-adaptive) ----------
__global__ __launch_bounds__(256) void store_out(const float* __restrict__ xout,
                                                 const int* __restrict__ cnt,
                                                 void* __restrict__ dout, int n) {
    int i = blockIdx.x * 256 + threadIdx.x;
    if (i >= n) return;
    if (*cnt == 0) ((bf16*)dout)[i] = __float2bfloat16(xout[i]);
    else           ((float*)dout)[i] = xout[i];
}

// ---------- conv1 + gelu + maxpool(14) ----------
// spec: [4,1,196,1000] fp32 (from arena); out pool1: [4,32,14,1000] fp32
__global__ __launch_bounds__(256) void conv1_pool(const float* __restrict__ spec,
                                                  const float* __restrict__ w1,
                                                  const float* __restrict__ b1,
                                                  float* __restrict__ pool1) {
    __shared__ float sw[25];
    int c = blockIdx.z & 31, b = blockIdx.z >> 5;
    int p = blockIdx.y;
    int j = blockIdx.x * 256 + threadIdx.x;
    if (threadIdx.x < 25) sw[threadIdx.x] = w1[c * 25 + threadIdx.x];
    __syncthreads();
    if (j >= TT) return;
    float bias = b1[c];
    float conv[14];
#pragma unroll
    for (int i = 0; i < 14; i++) conv[i] = bias;
    const float* sp = spec + (size_t)b * FBINS * TT;
    int ibase = p * 14;
    for (int ii = ibase - 2; ii <= ibase + 15; ii++) {
        if (ii < 0 || ii >= FBINS) continue;
        float v[5];
#pragma unroll
        for (int dj = 0; dj < 5; dj++) {
            int jj = j + dj - 2;
            v[dj] = (jj >= 0 && jj < TT) ? sp[(size_t)ii * TT + jj] : 0.f;
        }
        int il = ii - ibase;
#pragma unroll
        for (int di = 0; di < 5; di++) {
            int i = il - di + 2;
            if (i >= 0 && i < 14) {
#pragma unroll
                for (int dj = 0; dj < 5; dj++) conv[i] += v[dj] * sw[di * 5 + dj];
            }
        }
    }
    float m = -1e30f;
#pragma unroll
    for (int i = 0; i < 14; i++) m = fmaxf(m, gelu_f(conv[i]));
    pool1[(((size_t)b * 32 + c) * 14 + p) * TT + j] = m;
}

// ---------- conv2 + gelu + maxpool(14) + transpose ----------
// pool1: [4,32,14,1000] fp32 ; out p2t: [4000,64] fp32
__global__ __launch_bounds__(256) void conv2_pool(const float* __restrict__ pool1,
                                                  const float* __restrict__ w2,
                                                  const float* __restrict__ b2,
                                                  float* __restrict__ p2t) {
    __shared__ float sw[800];
    int c = blockIdx.y, b = blockIdx.z;
    for (int i = threadIdx.x; i < 800; i += 256) sw[i] = w2[(size_t)c * 800 + i];
    __syncthreads();
    float bias = b2[c];
    const float* pb = pool1 + (size_t)b * 32 * 14 * TT;
    for (int half = 0; half < 2; half++) {
        int j = blockIdx.x * 512 + half * 256 + threadIdx.x;
        if (j >= TT) continue;
        float conv[14];
#pragma unroll
        for (int i = 0; i < 14; i++) conv[i] = bias;
        for (int ci = 0; ci < 32; ci++) {
            const float* pc = pb + (size_t)ci * 14 * TT;
            const float* wc = sw + ci * 25;
            for (int ir = 0; ir < 14; ir++) {
                float v[5];
#pragma unroll
                for (int dj = 0; dj < 5; dj++) {
                    int jj = j + dj - 2;
                    v[dj] = (jj >= 0 && jj < TT) ? pc[(size_t)ir * TT + jj] : 0.f;
                }
#pragma unroll
                for (int di = 0; di < 5; di++) {
                    int i = ir - di + 2;
                    if (i >= 0 && i < 14) {
#pragma unroll
                        for (int dj = 0; dj < 5; dj++) conv[i] += v[dj] * wc[di * 5 + dj];
                    }
                }
            }
        }
        float m = -1e30f;
#pragma unroll
        for (int i = 0; i < 14; i++) m = fmaxf(m, gelu_f(conv[i]));
        p2t[((size_t)b * TT + j) * 64 + c] = m;
    }
}

// ---------- layernorm (all fp32) ----------
__global__ __launch_bounds__(256) void layernorm_k(const float* __restrict__ x,
                                                   const float* __restrict__ g,
                                                   const float* __restrict__ bta,
                                                   float* __restrict__ y) {
    __shared__ float red[256];
    int row = blockIdx.x, tid = threadIdx.x;
    const float* xr = x + (size_t)row * DM;
    float v0 = xr[tid], v1 = xr[tid + 256];
    red[tid] = v0 + v1;
    __syncthreads();
    for (int s = 128; s > 0; s >>= 1) { if (tid < s) red[tid] += red[tid + s]; __syncthreads(); }
    float mu = red[0] * (1.f / 512.f);
    __syncthreads();
    float d0 = v0 - mu, d1 = v1 - mu;
    red[tid] = d0 * d0 + d1 * d1;
    __syncthreads();
    for (int s = 128; s > 0; s >>= 1) { if (tid < s) red[tid] += red[tid + s]; __syncthreads(); }
    float rstd = rsqrtf(red[0] * (1.f / 512.f) + 1e-5f);
    float* yr = y + (size_t)row * DM;
    yr[tid]       = d0 * rstd * g[tid]       + bta[tid];
    yr[tid + 256] = d1 * rstd * g[tid + 256] + bta[tid + 256];
}

// ---------- generic NT GEMM (all fp32): C = act(A @ B^T + bias) [+ resid] ----------
template <int ACT>
__global__ __launch_bounds__(256) void gemm_nt(const float* __restrict__ A,
                                               const float* __restrict__ B,
                                               const float* __restrict__ bias,
                                               const float* __restrict__ resid,
                                               float* __restrict__ C,
                                               int M, int N, int K) {
    __shared__ __align__(16) float As[16][68];
    __shared__ __align__(16) float Bs[16][68];
    int tid = threadIdx.x;
    int tx = tid & 15, ty = tid >> 4;
    int m0 = blockIdx.x * 64, n0 = blockIdx.y * 64;
    float c[4][4] = {};
    for (int k0 = 0; k0 < K; k0 += 16) {
#pragma unroll
        for (int i = 0; i < 4; i++) {
            int idx = i * 256 + tid;
            int kk = idx & 15, r = idx >> 4;
            int gm = m0 + r;
            As[kk][r] = (gm < M) ? A[(size_t)gm * K + k0 + kk] : 0.f;
            int gn = n0 + r;  // N is a multiple of 64 in every call below
            Bs[kk][r] = B[(size_t)gn * K + k0 + kk];
        }
        __syncthreads();
#pragma unroll
        for (int k = 0; k < 16; k++) {
            float4 av = *(const float4*)&As[k][ty * 4];
            float4 bv = *(const float4*)&Bs[k][tx * 4];
            float a[4] = {av.x, av.y, av.z, av.w};
            float bq[4] = {bv.x, bv.y, bv.z, bv.w};
#pragma unroll
            for (int i = 0; i < 4; i++)
#pragma unroll
                for (int jj = 0; jj < 4; jj++) c[i][jj] += a[i] * bq[jj];
        }
        __syncthreads();
    }
#pragma unroll
    for (int i = 0; i < 4; i++) {
        int m = m0 + ty * 4 + i;
        if (m >= M) continue;
#pragma unroll
        for (int jj = 0; jj < 4; jj++) {
            int n = n0 + tx * 4 + jj;
            float v = c[i][jj] + bias[n];
            if (resid) v += resid[(size_t)m * N + n];
            if (ACT == 1) v = fmaxf(v, 0.f);
            C[(size_t)m * N + n] = v;
        }
    }
}

// ---------- fused attention with music-transformer skew (fp32) ----------
// Srel[s,t] = Q[s].Er[999-s+t]  (t<=s) ; 0 (t==s+1) ; Q[s+1].Er[t-s-2] (t>=s+2)
__global__ __launch_bounds__(256) void attn_k(const float* __restrict__ Q,
                                              const float* __restrict__ K,
                                              const float* __restrict__ V,
                                              const float* __restrict__ ErF,
                                              float* __restrict__ out) {
    __shared__ float sm[TT];
    __shared__ __align__(16) float sQ[64];
    __shared__ __align__(16) float sQ1[64];
    __shared__ float red[256];
    int s = blockIdx.x, bh = blockIdx.y;
    int b = bh >> 3, h = bh & 7;
    int tid = threadIdx.x;
    size_t qoff = ((size_t)(b * TT + s)) * DM + h * 64;
    if (tid < 64) sQ[tid] = Q[qoff + tid];
    else if (tid < 128) {
        int d = tid - 64;
        sQ1[d] = (s + 1 < TT) ? Q[qoff + DM + d] : 0.f;
    }
    __syncthreads();
    const float4* q4 = (const float4*)sQ;
    const float4* q14 = (const float4*)sQ1;
    for (int t = tid; t < TT; t += 256) {
        const float4* k4 = (const float4*)(K + ((size_t)(b * TT + t)) * DM + h * 64);
        float qk = 0.f;
#pragma unroll
        for (int d4 = 0; d4 < 16; d4++) {
            float4 a = q4[d4], kk = k4[d4];
            qk += a.x * kk.x + a.y * kk.y + a.z * kk.z + a.w * kk.w;
        }
        float rel = 0.f;
        if (t != s + 1) {
            int r; const float4* qe;
            if (t <= s) { r = TT - 1 - s + t; qe = q4; }
            else        { r = t - s - 2;      qe = q14; }
            const float4* e4 = (const float4*)(ErF + (size_t)r * 64);
#pragma unroll
            for (int d4 = 0; d4 < 16; d4++) {
                float4 a = qe[d4], ee = e4[d4];
                rel += a.x * ee.x + a.y * ee.y + a.z * ee.z + a.w * ee.w;
            }
        }
        sm[t] = (qk + rel) * 0.125f;  // 1/sqrt(64)
    }
    __syncthreads();
    float lm = -1e30f;
    for (int t = tid; t < TT; t += 256) lm = fmaxf(lm, sm[t]);
    red[tid] = lm;
    __syncthreads();
    for (int st = 128; st > 0; st >>= 1) { if (tid < st) red[tid] = fmaxf(red[tid], red[tid + st]); __syncthreads(); }
    float mx = red[0];
    __syncthreads();
    float lsum = 0.f;
    for (int t = tid; t < TT; t += 256) { float e = __expf(sm[t] - mx); sm[t] = e; lsum += e; }
    red[tid] = lsum;
    __syncthreads();
    for (int st = 128; st > 0; st >>= 1) { if (tid < st) red[tid] += red[tid + st]; __syncthreads(); }
    float denom = red[0];
    __syncthreads();
    int d = tid & 63, qq = tid >> 6;
    float acc = 0.f;
    int t0 = qq * 250;
    const float* vptr = V + ((size_t)b * TT) * DM + h * 64 + d;
    for (int t = t0; t < t0 + 250; t++) acc += sm[t] * vptr[(size_t)t * DM];
    red[tid] = acc;
    __syncthreads();
    if (tid < 64) {
        float o = (red[tid] + red[tid + 64] + red[tid + 128] + red[tid + 192]) / denom;
        out[qoff + tid] = o;
    }
}

// ---------- launch ----------
extern "C" void kernel_launch(void* const* d_in, const int* in_sizes, int n_in,
                              void* d_out, int out_size, void* d_ws, size_t ws_size,
                              hipStream_t stream) {
    // Safety net: fires only if the constructor's hipMalloc failed; the
    // correctness call precedes graph capture, so capture sees no malloc.
    if (!g_arena) (void)hipMalloc(&g_arena, ARENA_BYTES);
    float* A = (float*)g_arena;

    // Packed fp32 param arena: cumulative element offsets (input order).
    static const unsigned off[27] = {
        0, 784000, 784800, 784832, 836032, 836096, 868864, 869376, 871424,
        873472, 1922048, 2970624, 4019200, 5067776, 5069824, 5071872,
        5073920, 5075968, 5331968, 5334016, 5336064, 9530368, 9538560,
        13732864, 13734912, 13800448, 13800576};
    const float* spec  = A + off[0];
    const float* c1w   = A + off[1];
    const float* c1b   = A + off[2];
    const float* c2w   = A + off[3];
    const float* c2b   = A + off[4];
    const float* projw = A + off[5];
    const float* projb = A + off[6];
    const float* ln1g  = A + off[7];
    const float* ln1b  = A + off[8];
    const float* qw    = A + off[9];
    const float* kw    = A + off[10];
    const float* vw    = A + off[11];
    const float* dw    = A + off[12];
    const float* qb    = A + off[13];
    const float* kb    = A + off[14];
    const float* vb    = A + off[15];
    const float* db    = A + off[16];
    const float* Er    = A + off[17];
    const float* ln2g  = A + off[18];
    const float* ln2b  = A + off[19];
    const float* f1w   = A + off[20];
    const float* f1b   = A + off[21];
    const float* f2w   = A + off[22];
    const float* f2b_  = A + off[23];
    const float* depw  = A + off[24];
    const float* depb  = A + off[25];

    // Activations (dedicated, no aliasing except XOUT over dead P1):
    const size_t PA = 13800576;
    float* x    = A + PA;              // [4000,512]
    float* xn   = x  + 2048000;        // [4000,512]
    float* Qb   = xn + 2048000;
    float* Kb   = Qb + 2048000;
    float* Vb   = Kb + 2048000;
    float* AO   = Vb + 2048000;
    float* FFH  = AO + 2048000;        // [4000,2048]
    float* P1   = FFH + 8192000;       // [4,32,14,1000]
    float* P2T  = P1 + 1792000;        // [4000,64]
    float* XOUT = P1;                  // [4000,128] (P1 dead after conv2)
    int*   cnt  = (int*)(P2T + 256000);
    // end = (PA + 22,528,000 + 1) floats = 145.3 MB < 160 MB arena

    // 1. dtype sniff (cnt==0 <=> inputs are bf16)
    hipMemsetAsync(cnt, 0, sizeof(int), stream);
    sniff_k<<<1024, 256, 0, stream>>>((const unsigned short*)d_in[20], 1000000, cnt);

    // 2. convert all inputs to packed fp32
    CvtArgs ca;
    for (int i = 0; i < 26; i++) ca.src[i] = d_in[i];
    for (int i = 0; i < 27; i++) ca.off[i] = off[i];
    ca.cnt = cnt; ca.dst = A;
    cvt_all<<<(13800576 + 255) / 256, 256, 0, stream>>>(ca);

    // 3. conv frontend
    conv1_pool<<<dim3(4, 14, 128), 256, 0, stream>>>(spec, c1w, c1b, P1);
    conv2_pool<<<dim3(2, 64, 4), 256, 0, stream>>>(P1, c2w, c2b, P2T);
    gemm_nt<0><<<dim3(63, 8), 256, 0, stream>>>(P2T, projw, projb, nullptr, x, BT, DM, 64);

    // 4. transformer layers
    for (int l = 0; l < LL; l++) {
        layernorm_k<<<BT, 256, 0, stream>>>(x, ln1g + l * DM, ln1b + l * DM, xn);
        gemm_nt<0><<<dim3(63, 8), 256, 0, stream>>>(xn, qw + (size_t)l * DM * DM, qb + l * DM, nullptr, Qb, BT, DM, DM);
        gemm_nt<0><<<dim3(63, 8), 256, 0, stream>>>(xn, kw + (size_t)l * DM * DM, kb + l * DM, nullptr, Kb, BT, DM, DM);
        gemm_nt<0><<<dim3(63, 8), 256, 0, stream>>>(xn, vw + (size_t)l * DM * DM, vb + l * DM, nullptr, Vb, BT, DM, DM);
        attn_k<<<dim3(TT, BB * HH), 256, 0, stream>>>(Qb, Kb, Vb, Er + (size_t)l * TT * DEPTH, AO);
        gemm_nt<0><<<dim3(63, 8), 256, 0, stream>>>(AO, dw + (size_t)l * DM * DM, db + l * DM, x, x, BT, DM, DM);
        layernorm_k<<<BT, 256, 0, stream>>>(x, ln2g + l * DM, ln2b + l * DM, xn);
        gemm_nt<1><<<dim3(63, 32), 256, 0, stream>>>(xn, f1w + (size_t)l * FFN * DM, f1b + l * FFN, nullptr, FFH, BT, FFN, DM);
        gemm_nt<0><<<dim3(63, 8), 256, 0, stream>>>(FFH, f2w + (size_t)l * DM * FFN, f2b_ + l * DM, x, x, BT, DM, FFN);
    }

    // 5. deproj + dtype-adaptive output store
    gemm_nt<0><<<dim3(63, 2), 256, 0, stream>>>(x, depw, depb, nullptr, XOUT, BT, EDIM, DM);
    store_out<<<2000, 256, 0, stream>>>(XOUT, cnt, d_out, BT * EDIM);
}

// Round 6
// 4962.273 us; speedup vs baseline: 2.7761x; 2.7761x over previous
//
#include <hip/hip_runtime.h>
#include <hip/hip_bf16.h>
#include <math.h>

// ---------- constants ----------
#define BB 4
#define FBINS 196
#define TT 1000
#define DM 512
#define HH 8
#define DEPTH 64
#define FFN 2048
#define LL 4
#define EDIM 128
#define BT (BB*TT)   // 4000

typedef __hip_bfloat16 bf16;

// ---------- private arena (avoids any dependence on ws_size) ----------
#define ARENA_BYTES 420000000ULL
static void* g_arena = nullptr;
__attribute__((constructor)) static void arena_init() {
    if (!g_arena) (void)hipMalloc(&g_arena, ARENA_BYTES);
}

__device__ __forceinline__ float gelu_f(float x) {
    return 0.5f * x * (1.0f + erff(x * 0.70710678118654752440f));
}

// ---------- dtype sniffer (cnt==0 <=> inputs are bf16) ----------
__global__ __launch_bounds__(256) void sniff_k(const unsigned short* __restrict__ p,
                                               int n, int* __restrict__ cnt) {
    int i = blockIdx.x * 256 + threadIdx.x;
    int c = 0;
    for (; i < n; i += gridDim.x * 256) {
        unsigned short u = p[i];
        if ((unsigned short)(u & 0x7FFF) > (unsigned short)0x7F80) c++;
    }
    if (c) atomicAdd(cnt, c);
}

// ---------- convert all 26 inputs into packed fp32 params ----------
struct CvtArgs {
    const void* src[26];
    unsigned off[27];
    const int* cnt;
    float* dst;
};
__global__ __launch_bounds__(256) void cvt_all(CvtArgs a) {
    unsigned i = blockIdx.x * 256 + threadIdx.x;
    if (i >= a.off[26]) return;
    bool isb = (*a.cnt == 0);
    int w = 0;
    while (i >= a.off[w + 1]) w++;
    unsigned j = i - a.off[w];
    float v = isb ? __bfloat162float(((const bf16*)a.src[w])[j])
                  : ((const float*)a.src[w])[j];
    a.dst[i] = v;
}

// ---------- output store (dtype-adaptive) ----------
__global__ __launch_bounds__(256) void store_out(const float* __restrict__ xout,
                                                 const int* __restrict__ cnt,
                                                 void* __restrict__ dout, int n) {
    int i = blockIdx.x * 256 + threadIdx.x;
    if (i >= n) return;
    if (*cnt == 0) ((bf16*)dout)[i] = __float2bfloat16(xout[i]);
    else           ((float*)dout)[i] = xout[i];
}

// ---------- conv1 + gelu + maxpool(14) ----------
__global__ __launch_bounds__(256) void conv1_pool(const float* __restrict__ spec,
                                                  const float* __restrict__ w1,
                                                  const float* __restrict__ b1,
                                                  float* __restrict__ pool1) {
    __shared__ float sw[25];
    int c = blockIdx.z & 31, b = blockIdx.z >> 5;
    int p = blockIdx.y;
    int j = blockIdx.x * 256 + threadIdx.x;
    if (threadIdx.x < 25) sw[threadIdx.x] = w1[c * 25 + threadIdx.x];
    __syncthreads();
    if (j >= TT) return;
    float bias = b1[c];
    float conv[14];
#pragma unroll
    for (int i = 0; i < 14; i++) conv[i] = bias;
    const float* sp = spec + (size_t)b * FBINS * TT;
    int ibase = p * 14;
    for (int ii = ibase - 2; ii <= ibase + 15; ii++) {
        if (ii < 0 || ii >= FBINS) continue;
        float v[5];
#pragma unroll
        for (int dj = 0; dj < 5; dj++) {
            int jj = j + dj - 2;
            v[dj] = (jj >= 0 && jj < TT) ? sp[(size_t)ii * TT + jj] : 0.f;
        }
        int il = ii - ibase;
#pragma unroll
        for (int di = 0; di < 5; di++) {
            int i = il - di + 2;
            if (i >= 0 && i < 14) {
#pragma unroll
                for (int dj = 0; dj < 5; dj++) conv[i] += v[dj] * sw[di * 5 + dj];
            }
        }
    }
    float m = -1e30f;
#pragma unroll
    for (int i = 0; i < 14; i++) m = fmaxf(m, gelu_f(conv[i]));
    pool1[(((size_t)b * 32 + c) * 14 + p) * TT + j] = m;
}

// ---------- conv2 + gelu + maxpool(14) + transpose ----------
__global__ __launch_bounds__(256) void conv2_pool(const float* __restrict__ pool1,
                                                  const float* __restrict__ w2,
                                                  const float* __restrict__ b2,
                                                  float* __restrict__ p2t) {
    __shared__ float sw[800];
    int c = blockIdx.y, b = blockIdx.z;
    for (int i = threadIdx.x; i < 800; i += 256) sw[i] = w2[(size_t)c * 800 + i];
    __syncthreads();
    float bias = b2[c];
    const float* pb = pool1 + (size_t)b * 32 * 14 * TT;
    for (int half = 0; half < 2; half++) {
        int j = blockIdx.x * 512 + half * 256 + threadIdx.x;
        if (j >= TT) continue;
        float conv[14];
#pragma unroll
        for (int i = 0; i < 14; i++) conv[i] = bias;
        for (int ci = 0; ci < 32; ci++) {
            const float* pc = pb + (size_t)ci * 14 * TT;
            const float* wc = sw + ci * 25;
            for (int ir = 0; ir < 14; ir++) {
                float v[5];
#pragma unroll
                for (int dj = 0; dj < 5; dj++) {
                    int jj = j + dj - 2;
                    v[dj] = (jj >= 0 && jj < TT) ? pc[(size_t)ir * TT + jj] : 0.f;
                }
#pragma unroll
                for (int di = 0; di < 5; di++) {
                    int i = ir - di + 2;
                    if (i >= 0 && i < 14) {
#pragma unroll
                        for (int dj = 0; dj < 5; dj++) conv[i] += v[dj] * wc[di * 5 + dj];
                    }
                }
            }
        }
        float m = -1e30f;
#pragma unroll
        for (int i = 0; i < 14; i++) m = fmaxf(m, gelu_f(conv[i]));
        p2t[((size_t)b * TT + j) * 64 + c] = m;
    }
}

// ---------- layernorm ----------
__global__ __launch_bounds__(256) void layernorm_k(const float* __restrict__ x,
                                                   const float* __restrict__ g,
                                                   const float* __restrict__ bta,
                                                   float* __restrict__ y) {
    __shared__ float red[256];
    int row = blockIdx.x, tid = threadIdx.x;
    const float* xr = x + (size_t)row * DM;
    float v0 = xr[tid], v1 = xr[tid + 256];
    red[tid] = v0 + v1;
    __syncthreads();
    for (int s = 128; s > 0; s >>= 1) { if (tid < s) red[tid] += red[tid + s]; __syncthreads(); }
    float mu = red[0] * (1.f / 512.f);
    __syncthreads();
    float d0 = v0 - mu, d1 = v1 - mu;
    red[tid] = d0 * d0 + d1 * d1;
    __syncthreads();
    for (int s = 128; s > 0; s >>= 1) { if (tid < s) red[tid] += red[tid + s]; __syncthreads(); }
    float rstd = rsqrtf(red[0] * (1.f / 512.f) + 1e-5f);
    float* yr = y + (size_t)row * DM;
    yr[tid]       = d0 * rstd * g[tid]       + bta[tid];
    yr[tid + 256] = d1 * rstd * g[tid + 256] + bta[tid + 256];
}

// ---------- generic NT GEMM: C = act(A @ B^T + bias) [+ resid] ----------
template <int ACT>
__global__ __launch_bounds__(256) void gemm_nt(const float* __restrict__ A,
                                               const float* __restrict__ B,
                                               const float* __restrict__ bias,
                                               const float* __restrict__ resid,
                                               float* __restrict__ C,
                                               int M, int N, int K) {
    __shared__ __align__(16) float As[16][68];
    __shared__ __align__(16) float Bs[16][68];
    int tid = threadIdx.x;
    int tx = tid & 15, ty = tid >> 4;
    int m0 = blockIdx.x * 64, n0 = blockIdx.y * 64;
    float c[4][4] = {};
    for (int k0 = 0; k0 < K; k0 += 16) {
#pragma unroll
        for (int i = 0; i < 4; i++) {
            int idx = i * 256 + tid;
            int kk = idx & 15, r = idx >> 4;
            int gm = m0 + r;
            As[kk][r] = (gm < M) ? A[(size_t)gm * K + k0 + kk] : 0.f;
            int gn = n0 + r;
            Bs[kk][r] = B[(size_t)gn * K + k0 + kk];
        }
        __syncthreads();
#pragma unroll
        for (int k = 0; k < 16; k++) {
            float4 av = *(const float4*)&As[k][ty * 4];
            float4 bv = *(const float4*)&Bs[k][tx * 4];
            float a[4] = {av.x, av.y, av.z, av.w};
            float bq[4] = {bv.x, bv.y, bv.z, bv.w};
#pragma unroll
            for (int i = 0; i < 4; i++)
#pragma unroll
                for (int jj = 0; jj < 4; jj++) c[i][jj] += a[i] * bq[jj];
        }
        __syncthreads();
    }
#pragma unroll
    for (int i = 0; i < 4; i++) {
        int m = m0 + ty * 4 + i;
        if (m >= M) continue;
#pragma unroll
        for (int jj = 0; jj < 4; jj++) {
            int n = n0 + tx * 4 + jj;
            float v = c[i][jj] + bias[n];
            if (resid) v += resid[(size_t)m * N + n];
            if (ACT == 1) v = fmaxf(v, 0.f);
            C[(size_t)m * N + n] = v;
        }
    }
}

// ---------- batched attention GEMMs ----------
// Q/K/V layout: [b, t, h*64+d] (row stride DM). blockIdx.z = b*8+h.

// QErB[z, s, r] = sum_d Q[z][s,d] * Er[r,d]       grid (16,16,32)
__global__ __launch_bounds__(256) void qer_gemm(const float* __restrict__ Q,
                                                const float* __restrict__ Er,
                                                float* __restrict__ QErB) {
    __shared__ __align__(16) float As[16][68];
    __shared__ __align__(16) float Bs[16][68];
    int tid = threadIdx.x, tx = tid & 15, ty = tid >> 4;
    int m0 = blockIdx.x * 64, n0 = blockIdx.y * 64;
    int z = blockIdx.z, b = z >> 3, h = z & 7;
    const float* Ap = Q + (size_t)b * TT * DM + h * 64;
    float c[4][4] = {};
    for (int k0 = 0; k0 < 64; k0 += 16) {
#pragma unroll
        for (int i = 0; i < 4; i++) {
            int idx = i * 256 + tid, kk = idx & 15, r = idx >> 4;
            int gm = m0 + r;
            As[kk][r] = (gm < TT) ? Ap[(size_t)gm * DM + k0 + kk] : 0.f;
            int gn = n0 + r;
            Bs[kk][r] = (gn < TT) ? Er[(size_t)gn * 64 + k0 + kk] : 0.f;
        }
        __syncthreads();
#pragma unroll
        for (int k = 0; k < 16; k++) {
            float4 av = *(const float4*)&As[k][ty * 4];
            float4 bv = *(const float4*)&Bs[k][tx * 4];
            float a[4] = {av.x, av.y, av.z, av.w};
            float bq[4] = {bv.x, bv.y, bv.z, bv.w};
#pragma unroll
            for (int i = 0; i < 4; i++)
#pragma unroll
                for (int jj = 0; jj < 4; jj++) c[i][jj] += a[i] * bq[jj];
        }
        __syncthreads();
    }
    float* Cz = QErB + (size_t)z * 1000000;
#pragma unroll
    for (int i = 0; i < 4; i++) {
        int m = m0 + ty * 4 + i;
        if (m >= TT) continue;
#pragma unroll
        for (int jj = 0; jj < 4; jj++) {
            int n = n0 + tx * 4 + jj;
            if (n < TT) Cz[(size_t)m * TT + n] = c[i][jj];
        }
    }
}

// Sc[z, s, t] = (Q.K + Srel)*0.125, Srel gathered from QErB.   grid (16,16,32)
// Srel[s,t] = QErB[s,999-s+t] (t<=s) ; 0 (t==s+1) ; QErB[s+1,t-s-2] (t>=s+2)
__global__ __launch_bounds__(256) void score_gemm(const float* __restrict__ Q,
                                                  const float* __restrict__ K,
                                                  const float* __restrict__ QErB,
                                                  float* __restrict__ Sc) {
    __shared__ __align__(16) float As[16][68];
    __shared__ __align__(16) float Bs[16][68];
    int tid = threadIdx.x, tx = tid & 15, ty = tid >> 4;
    int m0 = blockIdx.x * 64, n0 = blockIdx.y * 64;
    int z = blockIdx.z, b = z >> 3, h = z & 7;
    const float* Ap = Q + (size_t)b * TT * DM + h * 64;
    const float* Bp = K + (size_t)b * TT * DM + h * 64;
    float c[4][4] = {};
    for (int k0 = 0; k0 < 64; k0 += 16) {
#pragma unroll
        for (int i = 0; i < 4; i++) {
            int idx = i * 256 + tid, kk = idx & 15, r = idx >> 4;
            int gm = m0 + r;
            As[kk][r] = (gm < TT) ? Ap[(size_t)gm * DM + k0 + kk] : 0.f;
            int gn = n0 + r;
            Bs[kk][r] = (gn < TT) ? Bp[(size_t)gn * DM + k0 + kk] : 0.f;
        }
        __syncthreads();
#pragma unroll
        for (int k = 0; k < 16; k++) {
            float4 av = *(const float4*)&As[k][ty * 4];
            float4 bv = *(const float4*)&Bs[k][tx * 4];
            float a[4] = {av.x, av.y, av.z, av.w};
            float bq[4] = {bv.x, bv.y, bv.z, bv.w};
#pragma unroll
            for (int i = 0; i < 4; i++)
#pragma unroll
                for (int jj = 0; jj < 4; jj++) c[i][jj] += a[i] * bq[jj];
        }
        __syncthreads();
    }
    const float* Ez = QErB + (size_t)z * 1000000;
    float* Cz = Sc + (size_t)z * 1000000;
#pragma unroll
    for (int i = 0; i < 4; i++) {
        int m = m0 + ty * 4 + i;      // s
        if (m >= TT) continue;
#pragma unroll
        for (int jj = 0; jj < 4; jj++) {
            int n = n0 + tx * 4 + jj; // t
            if (n >= TT) continue;
            float rel;
            if (n == m + 1)      rel = 0.f;
            else if (n <= m)     rel = Ez[(size_t)m * TT + (TT - 1 - m + n)];
            else                 rel = Ez[(size_t)(m + 1) * TT + (n - m - 2)];
            Cz[(size_t)m * TT + n] = (c[i][jj] + rel) * 0.125f;
        }
    }
}

// in-place row softmax over Sc, 32,000 rows of 1000
__global__ __launch_bounds__(256) void softmax_k(float* __restrict__ Sc) {
    __shared__ float red[256];
    float* row = Sc + (size_t)blockIdx.x * TT;
    int tid = threadIdx.x;
    float v[4]; float lm = -1e30f;
#pragma unroll
    for (int i = 0; i < 4; i++) {
        int t = tid + i * 256;
        v[i] = (t < TT) ? row[t] : -1e30f;
        lm = fmaxf(lm, v[i]);
    }
    red[tid] = lm; __syncthreads();
    for (int s = 128; s > 0; s >>= 1) { if (tid < s) red[tid] = fmaxf(red[tid], red[tid + s]); __syncthreads(); }
    float mx = red[0]; __syncthreads();
    float ls = 0.f;
#pragma unroll
    for (int i = 0; i < 4; i++) {
        int t = tid + i * 256;
        v[i] = (t < TT) ? __expf(v[i] - mx) : 0.f;
        ls += v[i];
    }
    red[tid] = ls; __syncthreads();
    for (int s = 128; s > 0; s >>= 1) { if (tid < s) red[tid] += red[tid + s]; __syncthreads(); }
    float inv = 1.f / red[0]; __syncthreads();
#pragma unroll
    for (int i = 0; i < 4; i++) {
        int t = tid + i * 256;
        if (t < TT) row[t] = v[i] * inv;
    }
}

// AO[b, s, h*64+d] = sum_t P[z][s,t] * V[b,t,h*64+d]     grid (16,1,32)
__global__ __launch_bounds__(256) void pv_gemm(const float* __restrict__ P,
                                               const float* __restrict__ V,
                                               float* __restrict__ AO) {
    __shared__ __align__(16) float As[16][68];
    __shared__ __align__(16) float Bs[16][68];
    int tid = threadIdx.x, tx = tid & 15, ty = tid >> 4;
    int m0 = blockIdx.x * 64;
    int z = blockIdx.z, b = z >> 3, h = z & 7;
    const float* Ap = P + (size_t)z * 1000000;         // lda 1000
    const float* Bp = V + (size_t)b * TT * DM + h * 64; // B[k,n] = Bp[k*DM+n]
    float c[4][4] = {};
    for (int k0 = 0; k0 < TT; k0 += 16) {
#pragma unroll
        for (int i = 0; i < 4; i++) {
            int idx = i * 256 + tid;
            { // A tile (NT-style indexing)
                int kk = idx & 15, r = idx >> 4;
                int gm = m0 + r, gk = k0 + kk;
                As[kk][r] = (gm < TT && gk < TT) ? Ap[(size_t)gm * TT + gk] : 0.f;
            }
            { // B tile (NN: coalesced rows of V)
                int r = idx & 63, kk = idx >> 6; // kk in [4i, 4i+3]
                int gk = k0 + kk;
                Bs[kk][r] = (gk < TT) ? Bp[(size_t)gk * DM + r] : 0.f;
            }
        }
        __syncthreads();
#pragma unroll
        for (int k = 0; k < 16; k++) {
            float4 av = *(const float4*)&As[k][ty * 4];
            float4 bv = *(const float4*)&Bs[k][tx * 4];
            float a[4] = {av.x, av.y, av.z, av.w};
            float bq[4] = {bv.x, bv.y, bv.z, bv.w};
#pragma unroll
            for (int i = 0; i < 4; i++)
#pragma unroll
                for (int jj = 0; jj < 4; jj++) c[i][jj] += a[i] * bq[jj];
        }
        __syncthreads();
    }
#pragma unroll
    for (int i = 0; i < 4; i++) {
        int m = m0 + ty * 4 + i;
        if (m >= TT) continue;
        float* Crow = AO + ((size_t)b * TT + m) * DM + h * 64;
#pragma unroll
        for (int jj = 0; jj < 4; jj++) Crow[tx * 4 + jj] = c[i][jj];
    }
}

// ---------- launch ----------
extern "C" void kernel_launch(void* const* d_in, const int* in_sizes, int n_in,
                              void* d_out, int out_size, void* d_ws, size_t ws_size,
                              hipStream_t stream) {
    if (!g_arena) (void)hipMalloc(&g_arena, ARENA_BYTES);
    float* A = (float*)g_arena;

    static const unsigned off[27] = {
        0, 784000, 784800, 784832, 836032, 836096, 868864, 869376, 871424,
        873472, 1922048, 2970624, 4019200, 5067776, 5069824, 5071872,
        5073920, 5075968, 5331968, 5334016, 5336064, 9530368, 9538560,
        13732864, 13734912, 13800448, 13800576};
    const float* spec  = A + off[0];
    const float* c1w   = A + off[1];
    const float* c1b   = A + off[2];
    const float* c2w   = A + off[3];
    const float* c2b   = A + off[4];
    const float* projw = A + off[5];
    const float* projb = A + off[6];
    const float* ln1g  = A + off[7];
    const float* ln1b  = A + off[8];
    const float* qw    = A + off[9];
    const float* kw    = A + off[10];
    const float* vw    = A + off[11];
    const float* dw    = A + off[12];
    const float* qb    = A + off[13];
    const float* kb    = A + off[14];
    const float* vb    = A + off[15];
    const float* db    = A + off[16];
    const float* Er    = A + off[17];
    const float* ln2g  = A + off[18];
    const float* ln2b  = A + off[19];
    const float* f1w   = A + off[20];
    const float* f1b   = A + off[21];
    const float* f2w   = A + off[22];
    const float* f2b_  = A + off[23];
    const float* depw  = A + off[24];
    const float* depb  = A + off[25];

    const size_t PA = 13800576;
    float* x    = A + PA;
    float* xn   = x  + 2048000;
    float* Qb   = xn + 2048000;
    float* Kb   = Qb + 2048000;
    float* Vb   = Kb + 2048000;
    float* AO   = Vb + 2048000;
    float* FFH  = AO + 2048000;        // [4000,2048]
    float* P1   = FFH + 8192000;       // conv scratch
    float* P2T  = P1 + 1792000;
    float* XOUT = P1;                  // alias (P1 dead after conv2)
    int*   cnt  = (int*)(P2T + 256000);
    float* QErB = P2T + 256016;        // [32,1000,1000]
    float* Sc   = QErB + 32000000;     // [32,1000,1000]
    // end = PA + 22,448,016 + 64,000,000 floats = 401.3 MB < 420 MB

    hipMemsetAsync(cnt, 0, sizeof(int), stream);
    sniff_k<<<1024, 256, 0, stream>>>((const unsigned short*)d_in[20], 1000000, cnt);

    CvtArgs ca;
    for (int i = 0; i < 26; i++) ca.src[i] = d_in[i];
    for (int i = 0; i < 27; i++) ca.off[i] = off[i];
    ca.cnt = cnt; ca.dst = A;
    cvt_all<<<(13800576 + 255) / 256, 256, 0, stream>>>(ca);

    conv1_pool<<<dim3(4, 14, 128), 256, 0, stream>>>(spec, c1w, c1b, P1);
    conv2_pool<<<dim3(2, 64, 4), 256, 0, stream>>>(P1, c2w, c2b, P2T);
    gemm_nt<0><<<dim3(63, 8), 256, 0, stream>>>(P2T, projw, projb, nullptr, x, BT, DM, 64);

    for (int l = 0; l < LL; l++) {
        layernorm_k<<<BT, 256, 0, stream>>>(x, ln1g + l * DM, ln1b + l * DM, xn);
        gemm_nt<0><<<dim3(63, 8), 256, 0, stream>>>(xn, qw + (size_t)l * DM * DM, qb + l * DM, nullptr, Qb, BT, DM, DM);
        gemm_nt<0><<<dim3(63, 8), 256, 0, stream>>>(xn, kw + (size_t)l * DM * DM, kb + l * DM, nullptr, Kb, BT, DM, DM);
        gemm_nt<0><<<dim3(63, 8), 256, 0, stream>>>(xn, vw + (size_t)l * DM * DM, vb + l * DM, nullptr, Vb, BT, DM, DM);
        // attention via batched GEMMs
        qer_gemm<<<dim3(16, 16, 32), 256, 0, stream>>>(Qb, Er + (size_t)l * TT * DEPTH, QErB);
        score_gemm<<<dim3(16, 16, 32), 256, 0, stream>>>(Qb, Kb, QErB, Sc);
        softmax_k<<<32000, 256, 0, stream>>>(Sc);
        pv_gemm<<<dim3(16, 1, 32), 256, 0, stream>>>(Sc, Vb, AO);
        gemm_nt<0><<<dim3(63, 8), 256, 0, stream>>>(AO, dw + (size_t)l * DM * DM, db + l * DM, x, x, BT, DM, DM);
        layernorm_k<<<BT, 256, 0, stream>>>(x, ln2g + l * DM, ln2b + l * DM, xn);
        gemm_nt<1><<<dim3(63, 32), 256, 0, stream>>>(xn, f1w + (size_t)l * FFN * DM, f1b + l * FFN, nullptr, FFH, BT, FFN, DM);
        gemm_nt<0><<<dim3(63, 8), 256, 0, stream>>>(FFH, f2w + (size_t)l * DM * FFN, f2b_ + l * DM, x, x, BT, DM, FFN);
    }

    gemm_nt<0><<<dim3(63, 2), 256, 0, stream>>>(x, depw, depb, nullptr, XOUT, BT, EDIM, DM);
    store_out<<<2000, 256, 0, stream>>>(XOUT, cnt, d_out, BT * EDIM);
}

// Round 7
// 2997.476 us; speedup vs baseline: 4.5958x; 1.6555x over previous
//
#include <hip/hip_runtime.h>
#include <hip/hip_bf16.h>
#include <math.h>

// ---------- constants ----------
#define BB 4
#define FBINS 196
#define TT 1000
#define DM 512
#define HH 8
#define DEPTH 64
#define FFN 2048
#define LL 4
#define EDIM 128
#define BT (BB*TT)   // 4000

typedef __hip_bfloat16 bf16;
typedef __attribute__((ext_vector_type(8))) short short8;
typedef __attribute__((ext_vector_type(4))) float floatx4;

// ---------- private arena ----------
#define ARENA_BYTES 420000000ULL
static void* g_arena = nullptr;
__attribute__((constructor)) static void arena_init() {
    if (!g_arena) (void)hipMalloc(&g_arena, ARENA_BYTES);
}

__device__ __forceinline__ float gelu_f(float x) {
    return 0.5f * x * (1.0f + erff(x * 0.70710678118654752440f));
}

// ---------- dtype sniffer (cnt==0 <=> inputs are bf16) ----------
__global__ __launch_bounds__(256) void sniff_k(const unsigned short* __restrict__ p,
                                               int n, int* __restrict__ cnt) {
    int i = blockIdx.x * 256 + threadIdx.x;
    int c = 0;
    for (; i < n; i += gridDim.x * 256) {
        unsigned short u = p[i];
        if ((unsigned short)(u & 0x7FFF) > (unsigned short)0x7F80) c++;
    }
    if (c) atomicAdd(cnt, c);
}

// ---------- convert all 26 inputs into packed fp32 params ----------
struct CvtArgs {
    const void* src[26];
    unsigned off[27];
    const int* cnt;
    float* dst;
};
__global__ __launch_bounds__(256) void cvt_all(CvtArgs a) {
    unsigned i = blockIdx.x * 256 + threadIdx.x;
    if (i >= a.off[26]) return;
    bool isb = (*a.cnt == 0);
    int w = 0;
    while (i >= a.off[w + 1]) w++;
    unsigned j = i - a.off[w];
    float v = isb ? __bfloat162float(((const bf16*)a.src[w])[j])
                  : ((const float*)a.src[w])[j];
    a.dst[i] = v;
}

// ---------- fp32 -> bf16 downcast ----------
__global__ __launch_bounds__(256) void f2bf_k(const float* __restrict__ s,
                                              bf16* __restrict__ d, int n) {
    int i = blockIdx.x * 256 + threadIdx.x;
    if (i < n) d[i] = __float2bfloat16(s[i]);
}

// ---------- output store (dtype-adaptive) ----------
__global__ __launch_bounds__(256) void store_out(const float* __restrict__ xout,
                                                 const int* __restrict__ cnt,
                                                 void* __restrict__ dout, int n) {
    int i = blockIdx.x * 256 + threadIdx.x;
    if (i >= n) return;
    if (*cnt == 0) ((bf16*)dout)[i] = __float2bfloat16(xout[i]);
    else           ((float*)dout)[i] = xout[i];
}

// ---------- conv1 + gelu + maxpool(14) ----------
__global__ __launch_bounds__(256) void conv1_pool(const float* __restrict__ spec,
                                                  const float* __restrict__ w1,
                                                  const float* __restrict__ b1,
                                                  float* __restrict__ pool1) {
    __shared__ float sw[25];
    int c = blockIdx.z & 31, b = blockIdx.z >> 5;
    int p = blockIdx.y;
    int j = blockIdx.x * 256 + threadIdx.x;
    if (threadIdx.x < 25) sw[threadIdx.x] = w1[c * 25 + threadIdx.x];
    __syncthreads();
    if (j >= TT) return;
    float bias = b1[c];
    float conv[14];
#pragma unroll
    for (int i = 0; i < 14; i++) conv[i] = bias;
    const float* sp = spec + (size_t)b * FBINS * TT;
    int ibase = p * 14;
    for (int ii = ibase - 2; ii <= ibase + 15; ii++) {
        if (ii < 0 || ii >= FBINS) continue;
        float v[5];
#pragma unroll
        for (int dj = 0; dj < 5; dj++) {
            int jj = j + dj - 2;
            v[dj] = (jj >= 0 && jj < TT) ? sp[(size_t)ii * TT + jj] : 0.f;
        }
        int il = ii - ibase;
#pragma unroll
        for (int di = 0; di < 5; di++) {
            int i = il - di + 2;
            if (i >= 0 && i < 14) {
#pragma unroll
                for (int dj = 0; dj < 5; dj++) conv[i] += v[dj] * sw[di * 5 + dj];
            }
        }
    }
    float m = -1e30f;
#pragma unroll
    for (int i = 0; i < 14; i++) m = fmaxf(m, gelu_f(conv[i]));
    pool1[(((size_t)b * 32 + c) * 14 + p) * TT + j] = m;
}

// ---------- conv2 + gelu + maxpool(14) + transpose ----------
__global__ __launch_bounds__(256) void conv2_pool(const float* __restrict__ pool1,
                                                  const float* __restrict__ w2,
                                                  const float* __restrict__ b2,
                                                  float* __restrict__ p2t) {
    __shared__ float sw[800];
    int c = blockIdx.y, b = blockIdx.z;
    for (int i = threadIdx.x; i < 800; i += 256) sw[i] = w2[(size_t)c * 800 + i];
    __syncthreads();
    float bias = b2[c];
    const float* pb = pool1 + (size_t)b * 32 * 14 * TT;
    for (int half = 0; half < 2; half++) {
        int j = blockIdx.x * 512 + half * 256 + threadIdx.x;
        if (j >= TT) continue;
        float conv[14];
#pragma unroll
        for (int i = 0; i < 14; i++) conv[i] = bias;
        for (int ci = 0; ci < 32; ci++) {
            const float* pc = pb + (size_t)ci * 14 * TT;
            const float* wc = sw + ci * 25;
            for (int ir = 0; ir < 14; ir++) {
                float v[5];
#pragma unroll
                for (int dj = 0; dj < 5; dj++) {
                    int jj = j + dj - 2;
                    v[dj] = (jj >= 0 && jj < TT) ? pc[(size_t)ir * TT + jj] : 0.f;
                }
#pragma unroll
                for (int di = 0; di < 5; di++) {
                    int i = ir - di + 2;
                    if (i >= 0 && i < 14) {
#pragma unroll
                        for (int dj = 0; dj < 5; dj++) conv[i] += v[dj] * wc[di * 5 + dj];
                    }
                }
            }
        }
        float m = -1e30f;
#pragma unroll
        for (int i = 0; i < 14; i++) m = fmaxf(m, gelu_f(conv[i]));
        p2t[((size_t)b * TT + j) * 64 + c] = m;
    }
}

// ---------- layernorm: fp32 in -> bf16 out ----------
__global__ __launch_bounds__(256) void layernorm_k(const float* __restrict__ x,
                                                   const float* __restrict__ g,
                                                   const float* __restrict__ bta,
                                                   bf16* __restrict__ y) {
    __shared__ float red[256];
    int row = blockIdx.x, tid = threadIdx.x;
    const float* xr = x + (size_t)row * DM;
    float v0 = xr[tid], v1 = xr[tid + 256];
    red[tid] = v0 + v1;
    __syncthreads();
    for (int s = 128; s > 0; s >>= 1) { if (tid < s) red[tid] += red[tid + s]; __syncthreads(); }
    float mu = red[0] * (1.f / 512.f);
    __syncthreads();
    float d0 = v0 - mu, d1 = v1 - mu;
    red[tid] = d0 * d0 + d1 * d1;
    __syncthreads();
    for (int s = 128; s > 0; s >>= 1) { if (tid < s) red[tid] += red[tid + s]; __syncthreads(); }
    float rstd = rsqrtf(red[0] * (1.f / 512.f) + 1e-5f);
    bf16* yr = y + (size_t)row * DM;
    yr[tid]       = __float2bfloat16(d0 * rstd * g[tid]       + bta[tid]);
    yr[tid + 256] = __float2bfloat16(d1 * rstd * g[tid + 256] + bta[tid + 256]);
}

// ---------- scalar NT GEMM (fp32), used for proj/deproj ----------
template <int ACT>
__global__ __launch_bounds__(256) void gemm_nt(const float* __restrict__ A,
                                               const float* __restrict__ B,
                                               const float* __restrict__ bias,
                                               const float* __restrict__ resid,
                                               float* __restrict__ C,
                                               int M, int N, int K) {
    __shared__ __align__(16) float As[16][68];
    __shared__ __align__(16) float Bs[16][68];
    int tid = threadIdx.x;
    int tx = tid & 15, ty = tid >> 4;
    int m0 = blockIdx.x * 64, n0 = blockIdx.y * 64;
    float c[4][4] = {};
    for (int k0 = 0; k0 < K; k0 += 16) {
#pragma unroll
        for (int i = 0; i < 4; i++) {
            int idx = i * 256 + tid;
            int kk = idx & 15, r = idx >> 4;
            int gm = m0 + r;
            As[kk][r] = (gm < M) ? A[(size_t)gm * K + k0 + kk] : 0.f;
            int gn = n0 + r;
            Bs[kk][r] = B[(size_t)gn * K + k0 + kk];
        }
        __syncthreads();
#pragma unroll
        for (int k = 0; k < 16; k++) {
            float4 av = *(const float4*)&As[k][ty * 4];
            float4 bv = *(const float4*)&Bs[k][tx * 4];
            float a[4] = {av.x, av.y, av.z, av.w};
            float bq[4] = {bv.x, bv.y, bv.z, bv.w};
#pragma unroll
            for (int i = 0; i < 4; i++)
#pragma unroll
                for (int jj = 0; jj < 4; jj++) c[i][jj] += a[i] * bq[jj];
        }
        __syncthreads();
    }
#pragma unroll
    for (int i = 0; i < 4; i++) {
        int m = m0 + ty * 4 + i;
        if (m >= M) continue;
#pragma unroll
        for (int jj = 0; jj < 4; jj++) {
            int n = n0 + tx * 4 + jj;
            float v = c[i][jj] + bias[n];
            if (resid) v += resid[(size_t)m * N + n];
            if (ACT == 1) v = fmaxf(v, 0.f);
            C[(size_t)m * N + n] = v;
        }
    }
}

// ---------- MFMA bf16 NT GEMM: C = act(A @ B^T + bias) [+ resid] ----------
// A: [M,K] bf16, B: [N,K] bf16 (N % 128 == 0, K % 32 == 0), bias fp32
// Tile 64(M) x 128(N), BK=32. 4 waves; wave w covers n-slice w*32..+31.
// mfma_f32_16x16x32_bf16: A[m=lane&15][k=quad*8+j]; C/D col=lane&15,row=quad*4+reg.
template <int ACT, bool OUT_BF16>
__global__ __launch_bounds__(256) void mfma_nt(const bf16* __restrict__ A,
                                               const bf16* __restrict__ B,
                                               const float* __restrict__ bias,
                                               const float* __restrict__ resid,
                                               float* __restrict__ Cf,
                                               bf16* __restrict__ Cb,
                                               int M, int N, int K) {
    __shared__ __align__(16) short Asm[64 * 40];    // stride 40 bf16 (80 B)
    __shared__ __align__(16) short Bsm[128 * 40];
    int tid = threadIdx.x;
    int wave = tid >> 6, lane = tid & 63;
    int q = lane >> 4, l15 = lane & 15;
    int m0 = blockIdx.x * 64, n0 = blockIdx.y * 128;
    int lrow = tid >> 2, lk = (tid & 3) * 8;
    floatx4 acc[4][2] = {};
    for (int k0 = 0; k0 < K; k0 += 32) {
        {   // stage A (64x32): one uint4 per thread
            int gm = m0 + lrow;
            uint4 v = make_uint4(0u, 0u, 0u, 0u);
            if (gm < M) v = *(const uint4*)(A + (size_t)gm * K + k0 + lk);
            *(uint4*)(Asm + lrow * 40 + lk) = v;
        }
        {   // stage B (128x32): two uint4 per thread
            int gn = n0 + lrow;
            *(uint4*)(Bsm + lrow * 40 + lk) =
                *(const uint4*)(B + (size_t)gn * K + k0 + lk);
            *(uint4*)(Bsm + (lrow + 64) * 40 + lk) =
                *(const uint4*)(B + (size_t)(gn + 64) * K + k0 + lk);
        }
        __syncthreads();
        short8 a[4], bf[2];
#pragma unroll
        for (int im = 0; im < 4; im++)
            a[im] = *(const short8*)(Asm + (im * 16 + l15) * 40 + q * 8);
#pragma unroll
        for (int jn = 0; jn < 2; jn++)
            bf[jn] = *(const short8*)(Bsm + (wave * 32 + jn * 16 + l15) * 40 + q * 8);
#pragma unroll
        for (int im = 0; im < 4; im++)
#pragma unroll
            for (int jn = 0; jn < 2; jn++)
                acc[im][jn] = __builtin_amdgcn_mfma_f32_16x16x32_bf16(
                    a[im], bf[jn], acc[im][jn], 0, 0, 0);
        __syncthreads();
    }
#pragma unroll
    for (int im = 0; im < 4; im++) {
#pragma unroll
        for (int jn = 0; jn < 2; jn++) {
            int n = n0 + wave * 32 + jn * 16 + l15;
            float bv = bias[n];
#pragma unroll
            for (int r = 0; r < 4; r++) {
                int m = m0 + im * 16 + q * 4 + r;
                if (m >= M) continue;
                float v = acc[im][jn][r] + bv;
                if (resid) v += resid[(size_t)m * N + n];
                if (ACT == 1) v = fmaxf(v, 0.f);
                if (OUT_BF16) Cb[(size_t)m * N + n] = __float2bfloat16(v);
                else          Cf[(size_t)m * N + n] = v;
            }
        }
    }
}

// ---------- batched attention GEMMs (fp32, unchanged math) ----------
// QErB[z, s, r] = sum_d Q[z][s,d] * Er[r,d]       grid (16,16,32)
__global__ __launch_bounds__(256) void qer_gemm(const float* __restrict__ Q,
                                                const float* __restrict__ Er,
                                                float* __restrict__ QErB) {
    __shared__ __align__(16) float As[16][68];
    __shared__ __align__(16) float Bs[16][68];
    int tid = threadIdx.x, tx = tid & 15, ty = tid >> 4;
    int m0 = blockIdx.x * 64, n0 = blockIdx.y * 64;
    int z = blockIdx.z, b = z >> 3, h = z & 7;
    const float* Ap = Q + (size_t)b * TT * DM + h * 64;
    float c[4][4] = {};
    for (int k0 = 0; k0 < 64; k0 += 16) {
#pragma unroll
        for (int i = 0; i < 4; i++) {
            int idx = i * 256 + tid, kk = idx & 15, r = idx >> 4;
            int gm = m0 + r;
            As[kk][r] = (gm < TT) ? Ap[(size_t)gm * DM + k0 + kk] : 0.f;
            int gn = n0 + r;
            Bs[kk][r] = (gn < TT) ? Er[(size_t)gn * 64 + k0 + kk] : 0.f;
        }
        __syncthreads();
#pragma unroll
        for (int k = 0; k < 16; k++) {
            float4 av = *(const float4*)&As[k][ty * 4];
            float4 bv = *(const float4*)&Bs[k][tx * 4];
            float a[4] = {av.x, av.y, av.z, av.w};
            float bq[4] = {bv.x, bv.y, bv.z, bv.w};
#pragma unroll
            for (int i = 0; i < 4; i++)
#pragma unroll
                for (int jj = 0; jj < 4; jj++) c[i][jj] += a[i] * bq[jj];
        }
        __syncthreads();
    }
    float* Cz = QErB + (size_t)z * 1000000;
#pragma unroll
    for (int i = 0; i < 4; i++) {
        int m = m0 + ty * 4 + i;
        if (m >= TT) continue;
#pragma unroll
        for (int jj = 0; jj < 4; jj++) {
            int n = n0 + tx * 4 + jj;
            if (n < TT) Cz[(size_t)m * TT + n] = c[i][jj];
        }
    }
}

// Sc[z, s, t] = (Q.K + Srel)*0.125 via skew gather.   grid (16,16,32)
__global__ __launch_bounds__(256) void score_gemm(const float* __restrict__ Q,
                                                  const float* __restrict__ K,
                                                  const float* __restrict__ QErB,
                                                  float* __restrict__ Sc) {
    __shared__ __align__(16) float As[16][68];
    __shared__ __align__(16) float Bs[16][68];
    int tid = threadIdx.x, tx = tid & 15, ty = tid >> 4;
    int m0 = blockIdx.x * 64, n0 = blockIdx.y * 64;
    int z = blockIdx.z, b = z >> 3, h = z & 7;
    const float* Ap = Q + (size_t)b * TT * DM + h * 64;
    const float* Bp = K + (size_t)b * TT * DM + h * 64;
    float c[4][4] = {};
    for (int k0 = 0; k0 < 64; k0 += 16) {
#pragma unroll
        for (int i = 0; i < 4; i++) {
            int idx = i * 256 + tid, kk = idx & 15, r = idx >> 4;
            int gm = m0 + r;
            As[kk][r] = (gm < TT) ? Ap[(size_t)gm * DM + k0 + kk] : 0.f;
            int gn = n0 + r;
            Bs[kk][r] = (gn < TT) ? Bp[(size_t)gn * DM + k0 + kk] : 0.f;
        }
        __syncthreads();
#pragma unroll
        for (int k = 0; k < 16; k++) {
            float4 av = *(const float4*)&As[k][ty * 4];
            float4 bv = *(const float4*)&Bs[k][tx * 4];
            float a[4] = {av.x, av.y, av.z, av.w};
            float bq[4] = {bv.x, bv.y, bv.z, bv.w};
#pragma unroll
            for (int i = 0; i < 4; i++)
#pragma unroll
                for (int jj = 0; jj < 4; jj++) c[i][jj] += a[i] * bq[jj];
        }
        __syncthreads();
    }
    const float* Ez = QErB + (size_t)z * 1000000;
    float* Cz = Sc + (size_t)z * 1000000;
#pragma unroll
    for (int i = 0; i < 4; i++) {
        int m = m0 + ty * 4 + i;
        if (m >= TT) continue;
#pragma unroll
        for (int jj = 0; jj < 4; jj++) {
            int n = n0 + tx * 4 + jj;
            if (n >= TT) continue;
            float rel;
            if (n == m + 1)      rel = 0.f;
            else if (n <= m)     rel = Ez[(size_t)m * TT + (TT - 1 - m + n)];
            else                 rel = Ez[(size_t)(m + 1) * TT + (n - m - 2)];
            Cz[(size_t)m * TT + n] = (c[i][jj] + rel) * 0.125f;
        }
    }
}

// in-place row softmax over Sc
__global__ __launch_bounds__(256) void softmax_k(float* __restrict__ Sc) {
    __shared__ float red[256];
    float* row = Sc + (size_t)blockIdx.x * TT;
    int tid = threadIdx.x;
    float v[4]; float lm = -1e30f;
#pragma unroll
    for (int i = 0; i < 4; i++) {
        int t = tid + i * 256;
        v[i] = (t < TT) ? row[t] : -1e30f;
        lm = fmaxf(lm, v[i]);
    }
    red[tid] = lm; __syncthreads();
    for (int s = 128; s > 0; s >>= 1) { if (tid < s) red[tid] = fmaxf(red[tid], red[tid + s]); __syncthreads(); }
    float mx = red[0]; __syncthreads();
    float ls = 0.f;
#pragma unroll
    for (int i = 0; i < 4; i++) {
        int t = tid + i * 256;
        v[i] = (t < TT) ? __expf(v[i] - mx) : 0.f;
        ls += v[i];
    }
    red[tid] = ls; __syncthreads();
    for (int s = 128; s > 0; s >>= 1) { if (tid < s) red[tid] += red[tid + s]; __syncthreads(); }
    float inv = 1.f / red[0]; __syncthreads();
#pragma unroll
    for (int i = 0; i < 4; i++) {
        int t = tid + i * 256;
        if (t < TT) row[t] = v[i] * inv;
    }
}

// AO_b[b, s, h*64+d] (bf16) = sum_t P[z][s,t] * V[b,t,h*64+d]   grid (16,1,32)
__global__ __launch_bounds__(256) void pv_gemm(const float* __restrict__ P,
                                               const float* __restrict__ V,
                                               bf16* __restrict__ AO) {
    __shared__ __align__(16) float As[16][68];
    __shared__ __align__(16) float Bs[16][68];
    int tid = threadIdx.x, tx = tid & 15, ty = tid >> 4;
    int m0 = blockIdx.x * 64;
    int z = blockIdx.z, b = z >> 3, h = z & 7;
    const float* Ap = P + (size_t)z * 1000000;
    const float* Bp = V + (size_t)b * TT * DM + h * 64;
    float c[4][4] = {};
    for (int k0 = 0; k0 < TT; k0 += 16) {
#pragma unroll
        for (int i = 0; i < 4; i++) {
            int idx = i * 256 + tid;
            {
                int kk = idx & 15, r = idx >> 4;
                int gm = m0 + r, gk = k0 + kk;
                As[kk][r] = (gm < TT && gk < TT) ? Ap[(size_t)gm * TT + gk] : 0.f;
            }
            {
                int r = idx & 63, kk = idx >> 6;
                int gk = k0 + kk;
                Bs[kk][r] = (gk < TT) ? Bp[(size_t)gk * DM + r] : 0.f;
            }
        }
        __syncthreads();
#pragma unroll
        for (int k = 0; k < 16; k++) {
            float4 av = *(const float4*)&As[k][ty * 4];
            float4 bv = *(const float4*)&Bs[k][tx * 4];
            float a[4] = {av.x, av.y, av.z, av.w};
            float bq[4] = {bv.x, bv.y, bv.z, bv.w};
#pragma unroll
            for (int i = 0; i < 4; i++)
#pragma unroll
                for (int jj = 0; jj < 4; jj++) c[i][jj] += a[i] * bq[jj];
        }
        __syncthreads();
    }
#pragma unroll
    for (int i = 0; i < 4; i++) {
        int m = m0 + ty * 4 + i;
        if (m >= TT) continue;
        bf16* Crow = AO + ((size_t)b * TT + m) * DM + h * 64;
#pragma unroll
        for (int jj = 0; jj < 4; jj++)
            Crow[tx * 4 + jj] = __float2bfloat16(c[i][jj]);
    }
}

// ---------- launch ----------
extern "C" void kernel_launch(void* const* d_in, const int* in_sizes, int n_in,
                              void* d_out, int out_size, void* d_ws, size_t ws_size,
                              hipStream_t stream) {
    if (!g_arena) (void)hipMalloc(&g_arena, ARENA_BYTES);
    float* A = (float*)g_arena;

    static const unsigned off[27] = {
        0, 784000, 784800, 784832, 836032, 836096, 868864, 869376, 871424,
        873472, 1922048, 2970624, 4019200, 5067776, 5069824, 5071872,
        5073920, 5075968, 5331968, 5334016, 5336064, 9530368, 9538560,
        13732864, 13734912, 13800448, 13800576};
    const float* spec  = A + off[0];
    const float* c1w   = A + off[1];
    const float* c1b   = A + off[2];
    const float* c2w   = A + off[3];
    const float* c2b   = A + off[4];
    const float* projw = A + off[5];
    const float* projb = A + off[6];
    const float* ln1g  = A + off[7];
    const float* ln1b  = A + off[8];
    const float* qwf   = A + off[9];   // qw|kw|vw|dw contiguous, 4x1,048,576
    const float* qb    = A + off[13];
    const float* kb    = A + off[14];
    const float* vb    = A + off[15];
    const float* db    = A + off[16];
    const float* Er    = A + off[17];
    const float* ln2g  = A + off[18];
    const float* ln2b  = A + off[19];
    const float* f1wf  = A + off[20];
    const float* f1b   = A + off[21];
    const float* f2wf  = A + off[22];
    const float* f2b_  = A + off[23];
    const float* depw  = A + off[24];
    const float* depb  = A + off[25];

    const size_t PA = 13800576;
    float* x    = A + PA;               // [4000,512] fp32 residual
    float* Qb   = x  + 2048000;         // fp32 (attention)
    float* Kb   = Qb + 2048000;
    float* Vb   = Kb + 2048000;
    float* P1   = Vb + 2048000;         // conv scratch [1,792,000]
    float* P2T  = P1 + 1792000;         // [256,000]
    float* XOUT = P1;                   // alias (P1 dead after conv2)
    int*   cnt  = (int*)(P2T + 256000);
    float* QErB = P2T + 256016;         // [32,1000,1000]
    float* Sc   = QErB + 32000000;      // [32,1000,1000]
    // bf16 regions (float-offset starts, all %4==0 -> 16B aligned)
    bf16* wb_qkvd = (bf16*)(Sc + 32000000);        // 4,194,304 bf16
    bf16* wb_f1   = (bf16*)(Sc + 32000000 + 2097152);
    bf16* wb_f2   = (bf16*)(Sc + 32000000 + 4194304);
    bf16* xn_b    = (bf16*)(Sc + 32000000 + 6291456);   // [4000,512]
    bf16* AO_b    = (bf16*)(Sc + 32000000 + 7315456);   // [4000,512]
    bf16* FFH_b   = (bf16*)(Sc + 32000000 + 8339456);   // [4000,2048]
    // end: PA+8,192,000+2,048,016+64,000,000+12,435,456 = 100,476,048 fl = 402 MB

    hipMemsetAsync(cnt, 0, sizeof(int), stream);
    sniff_k<<<1024, 256, 0, stream>>>((const unsigned short*)d_in[20], 1000000, cnt);

    CvtArgs ca;
    for (int i = 0; i < 26; i++) ca.src[i] = d_in[i];
    for (int i = 0; i < 27; i++) ca.off[i] = off[i];
    ca.cnt = cnt; ca.dst = A;
    cvt_all<<<(13800576 + 255) / 256, 256, 0, stream>>>(ca);

    // downcast big weights to bf16 once
    f2bf_k<<<16384, 256, 0, stream>>>(qwf,  wb_qkvd, 4194304);
    f2bf_k<<<16384, 256, 0, stream>>>(f1wf, wb_f1,   4194304);
    f2bf_k<<<16384, 256, 0, stream>>>(f2wf, wb_f2,   4194304);

    conv1_pool<<<dim3(4, 14, 128), 256, 0, stream>>>(spec, c1w, c1b, P1);
    conv2_pool<<<dim3(2, 64, 4), 256, 0, stream>>>(P1, c2w, c2b, P2T);
    gemm_nt<0><<<dim3(63, 8), 256, 0, stream>>>(P2T, projw, projb, nullptr, x, BT, DM, 64);

    const size_t WT = 1048576;  // per-tensor stride in wb_qkvd (L*DM*DM)
    for (int l = 0; l < LL; l++) {
        layernorm_k<<<BT, 256, 0, stream>>>(x, ln1g + l * DM, ln1b + l * DM, xn_b);
        mfma_nt<0, false><<<dim3(63, 4), 256, 0, stream>>>(
            xn_b, wb_qkvd + 0 * WT + (size_t)l * DM * DM, qb + l * DM, nullptr, Qb, nullptr, BT, DM, DM);
        mfma_nt<0, false><<<dim3(63, 4), 256, 0, stream>>>(
            xn_b, wb_qkvd + 1 * WT + (size_t)l * DM * DM, kb + l * DM, nullptr, Kb, nullptr, BT, DM, DM);
        mfma_nt<0, false><<<dim3(63, 4), 256, 0, stream>>>(
            xn_b, wb_qkvd + 2 * WT + (size_t)l * DM * DM, vb + l * DM, nullptr, Vb, nullptr, BT, DM, DM);
        qer_gemm<<<dim3(16, 16, 32), 256, 0, stream>>>(Qb, Er + (size_t)l * TT * DEPTH, QErB);
        score_gemm<<<dim3(16, 16, 32), 256, 0, stream>>>(Qb, Kb, QErB, Sc);
        softmax_k<<<32000, 256, 0, stream>>>(Sc);
        pv_gemm<<<dim3(16, 1, 32), 256, 0, stream>>>(Sc, Vb, AO_b);
        mfma_nt<0, false><<<dim3(63, 4), 256, 0, stream>>>(
            AO_b, wb_qkvd + 3 * WT + (size_t)l * DM * DM, db + l * DM, x, x, nullptr, BT, DM, DM);
        layernorm_k<<<BT, 256, 0, stream>>>(x, ln2g + l * DM, ln2b + l * DM, xn_b);
        mfma_nt<1, true><<<dim3(63, 16), 256, 0, stream>>>(
            xn_b, wb_f1 + (size_t)l * FFN * DM, f1b + l * FFN, nullptr, nullptr, FFH_b, BT, FFN, DM);
        mfma_nt<0, false><<<dim3(63, 4), 256, 0, stream>>>(
            FFH_b, wb_f2 + (size_t)l * DM * FFN, f2b_ + l * DM, x, x, nullptr, BT, DM, FFN);
    }

    gemm_nt<0><<<dim3(63, 2), 256, 0, stream>>>(x, depw, depb, nullptr, XOUT, BT, EDIM, DM);
    store_out<<<2000, 256, 0, stream>>>(XOUT, cnt, d_out, BT * EDIM);
}

// Round 8
// 1962.006 us; speedup vs baseline: 7.0213x; 1.5278x over previous
//
#include <hip/hip_runtime.h>
#include <hip/hip_bf16.h>
#include <math.h>

// ---------- constants ----------
#define BB 4
#define FBINS 196
#define TT 1000
#define DM 512
#define HH 8
#define DEPTH 64
#define FFN 2048
#define LL 4
#define EDIM 128
#define BT (BB*TT)   // 4000

typedef __hip_bfloat16 bf16;
typedef __attribute__((ext_vector_type(8))) short short8;
typedef __attribute__((ext_vector_type(4))) float floatx4;

// ---------- private arena ----------
#define ARENA_BYTES 420000000ULL
static void* g_arena = nullptr;
__attribute__((constructor)) static void arena_init() {
    if (!g_arena) (void)hipMalloc(&g_arena, ARENA_BYTES);
}

__device__ __forceinline__ float gelu_f(float x) {
    return 0.5f * x * (1.0f + erff(x * 0.70710678118654752440f));
}

// ---------- dtype sniffer (cnt==0 <=> inputs are bf16) ----------
__global__ __launch_bounds__(256) void sniff_k(const unsigned short* __restrict__ p,
                                               int n, int* __restrict__ cnt) {
    int i = blockIdx.x * 256 + threadIdx.x;
    int c = 0;
    for (; i < n; i += gridDim.x * 256) {
        unsigned short u = p[i];
        if ((unsigned short)(u & 0x7FFF) > (unsigned short)0x7F80) c++;
    }
    if (c) atomicAdd(cnt, c);
}

// ---------- convert all 26 inputs into packed fp32 params ----------
struct CvtArgs {
    const void* src[26];
    unsigned off[27];
    const int* cnt;
    float* dst;
};
__global__ __launch_bounds__(256) void cvt_all(CvtArgs a) {
    unsigned i = blockIdx.x * 256 + threadIdx.x;
    if (i >= a.off[26]) return;
    bool isb = (*a.cnt == 0);
    int w = 0;
    while (i >= a.off[w + 1]) w++;
    unsigned j = i - a.off[w];
    float v = isb ? __bfloat162float(((const bf16*)a.src[w])[j])
                  : ((const float*)a.src[w])[j];
    a.dst[i] = v;
}

// ---------- fp32 -> bf16 downcast ----------
__global__ __launch_bounds__(256) void f2bf_k(const float* __restrict__ s,
                                              bf16* __restrict__ d, int n) {
    int i = blockIdx.x * 256 + threadIdx.x;
    if (i < n) d[i] = __float2bfloat16(s[i]);
}

// ---------- output store (dtype-adaptive) ----------
__global__ __launch_bounds__(256) void store_out(const float* __restrict__ xout,
                                                 const int* __restrict__ cnt,
                                                 void* __restrict__ dout, int n) {
    int i = blockIdx.x * 256 + threadIdx.x;
    if (i >= n) return;
    if (*cnt == 0) ((bf16*)dout)[i] = __float2bfloat16(xout[i]);
    else           ((float*)dout)[i] = xout[i];
}

// ---------- conv1 + gelu + maxpool(14) ----------
__global__ __launch_bounds__(256) void conv1_pool(const float* __restrict__ spec,
                                                  const float* __restrict__ w1,
                                                  const float* __restrict__ b1,
                                                  float* __restrict__ pool1) {
    __shared__ float sw[25];
    int c = blockIdx.z & 31, b = blockIdx.z >> 5;
    int p = blockIdx.y;
    int j = blockIdx.x * 256 + threadIdx.x;
    if (threadIdx.x < 25) sw[threadIdx.x] = w1[c * 25 + threadIdx.x];
    __syncthreads();
    if (j >= TT) return;
    float bias = b1[c];
    float conv[14];
#pragma unroll
    for (int i = 0; i < 14; i++) conv[i] = bias;
    const float* sp = spec + (size_t)b * FBINS * TT;
    int ibase = p * 14;
    for (int ii = ibase - 2; ii <= ibase + 15; ii++) {
        if (ii < 0 || ii >= FBINS) continue;
        float v[5];
#pragma unroll
        for (int dj = 0; dj < 5; dj++) {
            int jj = j + dj - 2;
            v[dj] = (jj >= 0 && jj < TT) ? sp[(size_t)ii * TT + jj] : 0.f;
        }
        int il = ii - ibase;
#pragma unroll
        for (int di = 0; di < 5; di++) {
            int i = il - di + 2;
            if (i >= 0 && i < 14) {
#pragma unroll
                for (int dj = 0; dj < 5; dj++) conv[i] += v[dj] * sw[di * 5 + dj];
            }
        }
    }
    float m = -1e30f;
#pragma unroll
    for (int i = 0; i < 14; i++) m = fmaxf(m, gelu_f(conv[i]));
    pool1[(((size_t)b * 32 + c) * 14 + p) * TT + j] = m;
}

// ---------- conv2 + gelu + maxpool(14) + transpose ----------
__global__ __launch_bounds__(256) void conv2_pool(const float* __restrict__ pool1,
                                                  const float* __restrict__ w2,
                                                  const float* __restrict__ b2,
                                                  float* __restrict__ p2t) {
    __shared__ float sw[800];
    int c = blockIdx.y, b = blockIdx.z;
    for (int i = threadIdx.x; i < 800; i += 256) sw[i] = w2[(size_t)c * 800 + i];
    __syncthreads();
    float bias = b2[c];
    const float* pb = pool1 + (size_t)b * 32 * 14 * TT;
    for (int half = 0; half < 2; half++) {
        int j = blockIdx.x * 512 + half * 256 + threadIdx.x;
        if (j >= TT) continue;
        float conv[14];
#pragma unroll
        for (int i = 0; i < 14; i++) conv[i] = bias;
        for (int ci = 0; ci < 32; ci++) {
            const float* pc = pb + (size_t)ci * 14 * TT;
            const float* wc = sw + ci * 25;
            for (int ir = 0; ir < 14; ir++) {
                float v[5];
#pragma unroll
                for (int dj = 0; dj < 5; dj++) {
                    int jj = j + dj - 2;
                    v[dj] = (jj >= 0 && jj < TT) ? pc[(size_t)ir * TT + jj] : 0.f;
                }
#pragma unroll
                for (int di = 0; di < 5; di++) {
                    int i = ir - di + 2;
                    if (i >= 0 && i < 14) {
#pragma unroll
                        for (int dj = 0; dj < 5; dj++) conv[i] += v[dj] * wc[di * 5 + dj];
                    }
                }
            }
        }
        float m = -1e30f;
#pragma unroll
        for (int i = 0; i < 14; i++) m = fmaxf(m, gelu_f(conv[i]));
        p2t[((size_t)b * TT + j) * 64 + c] = m;
    }
}

// ---------- layernorm: fp32 in -> bf16 out ----------
__global__ __launch_bounds__(256) void layernorm_k(const float* __restrict__ x,
                                                   const float* __restrict__ g,
                                                   const float* __restrict__ bta,
                                                   bf16* __restrict__ y) {
    __shared__ float red[256];
    int row = blockIdx.x, tid = threadIdx.x;
    const float* xr = x + (size_t)row * DM;
    float v0 = xr[tid], v1 = xr[tid + 256];
    red[tid] = v0 + v1;
    __syncthreads();
    for (int s = 128; s > 0; s >>= 1) { if (tid < s) red[tid] += red[tid + s]; __syncthreads(); }
    float mu = red[0] * (1.f / 512.f);
    __syncthreads();
    float d0 = v0 - mu, d1 = v1 - mu;
    red[tid] = d0 * d0 + d1 * d1;
    __syncthreads();
    for (int s = 128; s > 0; s >>= 1) { if (tid < s) red[tid] += red[tid + s]; __syncthreads(); }
    float rstd = rsqrtf(red[0] * (1.f / 512.f) + 1e-5f);
    bf16* yr = y + (size_t)row * DM;
    yr[tid]       = __float2bfloat16(d0 * rstd * g[tid]       + bta[tid]);
    yr[tid + 256] = __float2bfloat16(d1 * rstd * g[tid + 256] + bta[tid + 256]);
}

// ---------- scalar NT GEMM (fp32), used for proj/deproj ----------
template <int ACT>
__global__ __launch_bounds__(256) void gemm_nt(const float* __restrict__ A,
                                               const float* __restrict__ B,
                                               const float* __restrict__ bias,
                                               const float* __restrict__ resid,
                                               float* __restrict__ C,
                                               int M, int N, int K) {
    __shared__ __align__(16) float As[16][68];
    __shared__ __align__(16) float Bs[16][68];
    int tid = threadIdx.x;
    int tx = tid & 15, ty = tid >> 4;
    int m0 = blockIdx.x * 64, n0 = blockIdx.y * 64;
    float c[4][4] = {};
    for (int k0 = 0; k0 < K; k0 += 16) {
#pragma unroll
        for (int i = 0; i < 4; i++) {
            int idx = i * 256 + tid;
            int kk = idx & 15, r = idx >> 4;
            int gm = m0 + r;
            As[kk][r] = (gm < M) ? A[(size_t)gm * K + k0 + kk] : 0.f;
            int gn = n0 + r;
            Bs[kk][r] = B[(size_t)gn * K + k0 + kk];
        }
        __syncthreads();
#pragma unroll
        for (int k = 0; k < 16; k++) {
            float4 av = *(const float4*)&As[k][ty * 4];
            float4 bv = *(const float4*)&Bs[k][tx * 4];
            float a[4] = {av.x, av.y, av.z, av.w};
            float bq[4] = {bv.x, bv.y, bv.z, bv.w};
#pragma unroll
            for (int i = 0; i < 4; i++)
#pragma unroll
                for (int jj = 0; jj < 4; jj++) c[i][jj] += a[i] * bq[jj];
        }
        __syncthreads();
    }
#pragma unroll
    for (int i = 0; i < 4; i++) {
        int m = m0 + ty * 4 + i;
        if (m >= M) continue;
#pragma unroll
        for (int jj = 0; jj < 4; jj++) {
            int n = n0 + tx * 4 + jj;
            float v = c[i][jj] + bias[n];
            if (resid) v += resid[(size_t)m * N + n];
            if (ACT == 1) v = fmaxf(v, 0.f);
            C[(size_t)m * N + n] = v;
        }
    }
}

// ---------- MFMA bf16 NT GEMM (weights): C = act(A @ B^T + bias) [+ resid] ----------
// Tile 64(M) x 128(N), BK=32. 4 waves; wave w covers n-slice w*32..+31.
template <int ACT, bool OUT_BF16>
__global__ __launch_bounds__(256) void mfma_nt(const bf16* __restrict__ A,
                                               const bf16* __restrict__ B,
                                               const float* __restrict__ bias,
                                               const float* __restrict__ resid,
                                               float* __restrict__ Cf,
                                               bf16* __restrict__ Cb,
                                               int M, int N, int K) {
    __shared__ __align__(16) short Asm[64 * 40];
    __shared__ __align__(16) short Bsm[128 * 40];
    int tid = threadIdx.x;
    int wave = tid >> 6, lane = tid & 63;
    int q = lane >> 4, l15 = lane & 15;
    int m0 = blockIdx.x * 64, n0 = blockIdx.y * 128;
    int lrow = tid >> 2, lk = (tid & 3) * 8;
    floatx4 acc[4][2] = {};
    for (int k0 = 0; k0 < K; k0 += 32) {
        {
            int gm = m0 + lrow;
            uint4 v = make_uint4(0u, 0u, 0u, 0u);
            if (gm < M) v = *(const uint4*)(A + (size_t)gm * K + k0 + lk);
            *(uint4*)(Asm + lrow * 40 + lk) = v;
        }
        {
            int gn = n0 + lrow;
            *(uint4*)(Bsm + lrow * 40 + lk) =
                *(const uint4*)(B + (size_t)gn * K + k0 + lk);
            *(uint4*)(Bsm + (lrow + 64) * 40 + lk) =
                *(const uint4*)(B + (size_t)(gn + 64) * K + k0 + lk);
        }
        __syncthreads();
        short8 a[4], bf[2];
#pragma unroll
        for (int im = 0; im < 4; im++)
            a[im] = *(const short8*)(Asm + (im * 16 + l15) * 40 + q * 8);
#pragma unroll
        for (int jn = 0; jn < 2; jn++)
            bf[jn] = *(const short8*)(Bsm + (wave * 32 + jn * 16 + l15) * 40 + q * 8);
#pragma unroll
        for (int im = 0; im < 4; im++)
#pragma unroll
            for (int jn = 0; jn < 2; jn++)
                acc[im][jn] = __builtin_amdgcn_mfma_f32_16x16x32_bf16(
                    a[im], bf[jn], acc[im][jn], 0, 0, 0);
        __syncthreads();
    }
#pragma unroll
    for (int im = 0; im < 4; im++) {
#pragma unroll
        for (int jn = 0; jn < 2; jn++) {
            int n = n0 + wave * 32 + jn * 16 + l15;
            float bv = bias[n];
#pragma unroll
            for (int r = 0; r < 4; r++) {
                int m = m0 + im * 16 + q * 4 + r;
                if (m >= M) continue;
                float v = acc[im][jn][r] + bv;
                if (resid) v += resid[(size_t)m * N + n];
                if (ACT == 1) v = fmaxf(v, 0.f);
                if (OUT_BF16) Cb[(size_t)m * N + n] = __float2bfloat16(v);
                else          Cf[(size_t)m * N + n] = v;
            }
        }
    }
}

// ---------- V transpose: Vb[b,t,h*64+d] -> Vt[z][d][t] (stride 1024, zero-pad t) ----
__global__ __launch_bounds__(256) void vt_k(const bf16* __restrict__ Vb,
                                            bf16* __restrict__ Vt) {
    __shared__ short tile[64][65];
    int t0 = blockIdx.x * 64, z = blockIdx.y;
    int b = z >> 3, h = z & 7;
    int tid = threadIdx.x;
#pragma unroll
    for (int i = 0; i < 16; i++) {
        int tr = i * 4 + (tid >> 6), d = tid & 63;
        int t = t0 + tr;
        bf16 v = (t < TT) ? Vb[((size_t)b * TT + t) * DM + h * 64 + d] : (bf16)__float2bfloat16(0.f);
        tile[tr][d] = *(short*)&v;
    }
    __syncthreads();
#pragma unroll
    for (int i = 0; i < 16; i++) {
        int dr = i * 4 + (tid >> 6), tc = tid & 63;
        *(short*)&Vt[(size_t)z * 65536 + dr * 1024 + t0 + tc] = tile[tc][dr];
    }
}

// ---------- qer MFMA: QErB_b[z,s,r] = Q[z][s,:].Er[r,:]  grid (16,8,32) ----------
__global__ __launch_bounds__(256) void qer_mfma(const bf16* __restrict__ Q,
                                                const bf16* __restrict__ Er,
                                                bf16* __restrict__ QErB) {
    __shared__ __align__(16) short Asm[64 * 40];
    __shared__ __align__(16) short Bsm[128 * 40];
    int tid = threadIdx.x;
    int wave = tid >> 6, lane = tid & 63;
    int q = lane >> 4, l15 = lane & 15;
    int m0 = blockIdx.x * 64, n0 = blockIdx.y * 128;
    int z = blockIdx.z, b = z >> 3, h = z & 7;
    const bf16* Ap = Q + (size_t)b * TT * DM + h * 64;
    int lrow = tid >> 2, lk = (tid & 3) * 8;
    floatx4 acc[4][2] = {};
    for (int k0 = 0; k0 < 64; k0 += 32) {
        {
            int gm = m0 + lrow;
            uint4 v = make_uint4(0u, 0u, 0u, 0u);
            if (gm < TT) v = *(const uint4*)(Ap + (size_t)gm * DM + k0 + lk);
            *(uint4*)(Asm + lrow * 40 + lk) = v;
        }
        {
            int gn = n0 + lrow;
            uint4 v0 = make_uint4(0u, 0u, 0u, 0u), v1 = v0;
            if (gn < TT)      v0 = *(const uint4*)(Er + (size_t)gn * 64 + k0 + lk);
            if (gn + 64 < TT) v1 = *(const uint4*)(Er + (size_t)(gn + 64) * 64 + k0 + lk);
            *(uint4*)(Bsm + lrow * 40 + lk) = v0;
            *(uint4*)(Bsm + (lrow + 64) * 40 + lk) = v1;
        }
        __syncthreads();
        short8 a[4], bf[2];
#pragma unroll
        for (int im = 0; im < 4; im++)
            a[im] = *(const short8*)(Asm + (im * 16 + l15) * 40 + q * 8);
#pragma unroll
        for (int jn = 0; jn < 2; jn++)
            bf[jn] = *(const short8*)(Bsm + (wave * 32 + jn * 16 + l15) * 40 + q * 8);
#pragma unroll
        for (int im = 0; im < 4; im++)
#pragma unroll
            for (int jn = 0; jn < 2; jn++)
                acc[im][jn] = __builtin_amdgcn_mfma_f32_16x16x32_bf16(
                    a[im], bf[jn], acc[im][jn], 0, 0, 0);
        __syncthreads();
    }
    bf16* Cz = QErB + (size_t)z * 1000000;
#pragma unroll
    for (int im = 0; im < 4; im++) {
#pragma unroll
        for (int jn = 0; jn < 2; jn++) {
            int n = n0 + wave * 32 + jn * 16 + l15;
            if (n >= TT) continue;
#pragma unroll
            for (int r = 0; r < 4; r++) {
                int m = m0 + im * 16 + q * 4 + r;
                if (m < TT) Cz[(size_t)m * TT + n] = __float2bfloat16(acc[im][jn][r]);
            }
        }
    }
}

// ---------- score MFMA + skew epilogue: Sc = (Q.K^T + Srel)*0.125  grid (16,8,32) --
__global__ __launch_bounds__(256) void score_mfma(const bf16* __restrict__ Q,
                                                  const bf16* __restrict__ K,
                                                  const bf16* __restrict__ QErB,
                                                  float* __restrict__ Sc) {
    __shared__ __align__(16) short Asm[64 * 40];
    __shared__ __align__(16) short Bsm[128 * 40];
    int tid = threadIdx.x;
    int wave = tid >> 6, lane = tid & 63;
    int q = lane >> 4, l15 = lane & 15;
    int m0 = blockIdx.x * 64, n0 = blockIdx.y * 128;
    int z = blockIdx.z, b = z >> 3, h = z & 7;
    const bf16* Ap = Q + (size_t)b * TT * DM + h * 64;
    const bf16* Bp = K + (size_t)b * TT * DM + h * 64;
    int lrow = tid >> 2, lk = (tid & 3) * 8;
    floatx4 acc[4][2] = {};
    for (int k0 = 0; k0 < 64; k0 += 32) {
        {
            int gm = m0 + lrow;
            uint4 v = make_uint4(0u, 0u, 0u, 0u);
            if (gm < TT) v = *(const uint4*)(Ap + (size_t)gm * DM + k0 + lk);
            *(uint4*)(Asm + lrow * 40 + lk) = v;
        }
        {
            int gn = n0 + lrow;
            uint4 v0 = make_uint4(0u, 0u, 0u, 0u), v1 = v0;
            if (gn < TT)      v0 = *(const uint4*)(Bp + (size_t)gn * DM + k0 + lk);
            if (gn + 64 < TT) v1 = *(const uint4*)(Bp + (size_t)(gn + 64) * DM + k0 + lk);
            *(uint4*)(Bsm + lrow * 40 + lk) = v0;
            *(uint4*)(Bsm + (lrow + 64) * 40 + lk) = v1;
        }
        __syncthreads();
        short8 a[4], bf[2];
#pragma unroll
        for (int im = 0; im < 4; im++)
            a[im] = *(const short8*)(Asm + (im * 16 + l15) * 40 + q * 8);
#pragma unroll
        for (int jn = 0; jn < 2; jn++)
            bf[jn] = *(const short8*)(Bsm + (wave * 32 + jn * 16 + l15) * 40 + q * 8);
#pragma unroll
        for (int im = 0; im < 4; im++)
#pragma unroll
            for (int jn = 0; jn < 2; jn++)
                acc[im][jn] = __builtin_amdgcn_mfma_f32_16x16x32_bf16(
                    a[im], bf[jn], acc[im][jn], 0, 0, 0);
        __syncthreads();
    }
    const bf16* Ez = QErB + (size_t)z * 1000000;
    float* Cz = Sc + (size_t)z * 1000000;
#pragma unroll
    for (int im = 0; im < 4; im++) {
#pragma unroll
        for (int jn = 0; jn < 2; jn++) {
            int n = n0 + wave * 32 + jn * 16 + l15;   // t
            if (n >= TT) continue;
#pragma unroll
            for (int r = 0; r < 4; r++) {
                int m = m0 + im * 16 + q * 4 + r;     // s
                if (m >= TT) continue;
                float rel;
                if (n == m + 1)  rel = 0.f;
                else if (n <= m) rel = __bfloat162float(Ez[(size_t)m * TT + (TT - 1 - m + n)]);
                else             rel = __bfloat162float(Ez[(size_t)(m + 1) * TT + (n - m - 2)]);
                Cz[(size_t)m * TT + n] = (acc[im][jn][r] + rel) * 0.125f;
            }
        }
    }
}

// ---------- softmax: Sc fp32 (stride 1000) -> Pb bf16 (stride 1024, zero-padded) ----
__global__ __launch_bounds__(256) void softmax_k(const float* __restrict__ Sc,
                                                 bf16* __restrict__ Pb) {
    __shared__ float red[256];
    const float* row = Sc + (size_t)blockIdx.x * TT;
    bf16* prow = Pb + (size_t)blockIdx.x * 1024;
    int tid = threadIdx.x;
    float v[4]; float lm = -1e30f;
#pragma unroll
    for (int i = 0; i < 4; i++) {
        int t = tid + i * 256;
        v[i] = (t < TT) ? row[t] : -1e30f;
        lm = fmaxf(lm, v[i]);
    }
    red[tid] = lm; __syncthreads();
    for (int s = 128; s > 0; s >>= 1) { if (tid < s) red[tid] = fmaxf(red[tid], red[tid + s]); __syncthreads(); }
    float mx = red[0]; __syncthreads();
    float ls = 0.f;
#pragma unroll
    for (int i = 0; i < 4; i++) {
        int t = tid + i * 256;
        v[i] = (t < TT) ? __expf(v[i] - mx) : 0.f;
        ls += v[i];
    }
    red[tid] = ls; __syncthreads();
    for (int s = 128; s > 0; s >>= 1) { if (tid < s) red[tid] += red[tid + s]; __syncthreads(); }
    float inv = 1.f / red[0]; __syncthreads();
#pragma unroll
    for (int i = 0; i < 4; i++) {
        int t = tid + i * 256;
        prow[t] = __float2bfloat16(v[i] * inv);   // t>=1000 -> 0 (v[i]=0)
    }
}

// ---------- pv MFMA: AO[b,s,h*64+d] = P[z] @ Vt[z]^T   grid (16,1,32) ----------
// P: [1000 x 1024] bf16 (k=t, zero-padded). Vt: [64 x 1024] bf16 per z.
__global__ __launch_bounds__(256) void pv_mfma(const bf16* __restrict__ P,
                                               const bf16* __restrict__ Vt,
                                               bf16* __restrict__ AO) {
    __shared__ __align__(16) short Asm[64 * 40];
    __shared__ __align__(16) short Bsm[64 * 40];
    int tid = threadIdx.x;
    int wave = tid >> 6, lane = tid & 63;
    int q = lane >> 4, l15 = lane & 15;
    int m0 = blockIdx.x * 64;
    int z = blockIdx.z, b = z >> 3, h = z & 7;
    const bf16* Ap = P + (size_t)z * 1024000;
    const bf16* Bp = Vt + (size_t)z * 65536;
    int lrow = tid >> 2, lk = (tid & 3) * 8;
    floatx4 acc[4] = {};
    for (int k0 = 0; k0 < 1024; k0 += 32) {
        {
            int gm = m0 + lrow;
            uint4 v = make_uint4(0u, 0u, 0u, 0u);
            if (gm < TT) v = *(const uint4*)(Ap + (size_t)gm * 1024 + k0 + lk);
            *(uint4*)(Asm + lrow * 40 + lk) = v;
        }
        *(uint4*)(Bsm + lrow * 40 + lk) =
            *(const uint4*)(Bp + (size_t)lrow * 1024 + k0 + lk);
        __syncthreads();
        short8 a = *(const short8*)(Asm + (wave * 16 + l15) * 40 + q * 8);
#pragma unroll
        for (int jn = 0; jn < 4; jn++) {
            short8 bf = *(const short8*)(Bsm + (jn * 16 + l15) * 40 + q * 8);
            acc[jn] = __builtin_amdgcn_mfma_f32_16x16x32_bf16(a, bf, acc[jn], 0, 0, 0);
        }
        __syncthreads();
    }
#pragma unroll
    for (int jn = 0; jn < 4; jn++) {
        int n = jn * 16 + l15;  // d
#pragma unroll
        for (int r = 0; r < 4; r++) {
            int m = m0 + wave * 16 + q * 4 + r;   // s
            if (m < TT)
                AO[((size_t)b * TT + m) * DM + h * 64 + n] = __float2bfloat16(acc[jn][r]);
        }
    }
}

// ---------- launch ----------
extern "C" void kernel_launch(void* const* d_in, const int* in_sizes, int n_in,
                              void* d_out, int out_size, void* d_ws, size_t ws_size,
                              hipStream_t stream) {
    if (!g_arena) (void)hipMalloc(&g_arena, ARENA_BYTES);
    float* A = (float*)g_arena;

    static const unsigned off[27] = {
        0, 784000, 784800, 784832, 836032, 836096, 868864, 869376, 871424,
        873472, 1922048, 2970624, 4019200, 5067776, 5069824, 5071872,
        5073920, 5075968, 5331968, 5334016, 5336064, 9530368, 9538560,
        13732864, 13734912, 13800448, 13800576};
    const float* spec  = A + off[0];
    const float* c1w   = A + off[1];
    const float* c1b   = A + off[2];
    const float* c2w   = A + off[3];
    const float* c2b   = A + off[4];
    const float* projw = A + off[5];
    const float* projb = A + off[6];
    const float* ln1g  = A + off[7];
    const float* ln1b  = A + off[8];
    const float* qwf   = A + off[9];   // qw|kw|vw|dw contiguous
    const float* qb    = A + off[13];
    const float* kb    = A + off[14];
    const float* vb    = A + off[15];
    const float* db    = A + off[16];
    const float* Erf   = A + off[17];
    const float* ln2g  = A + off[18];
    const float* ln2b  = A + off[19];
    const float* f1wf  = A + off[20];
    const float* f1b   = A + off[21];
    const float* f2wf  = A + off[22];
    const float* f2b_  = A + off[23];
    const float* depw  = A + off[24];
    const float* depb  = A + off[25];

    // ---- arena layout (float offsets; all bf16 starts %4==0 -> 16B aligned) ----
    const size_t PA = 13800576;
    float* x    = A + PA;                     // [4000,512] fp32
    float* P1   = x + 2048000;                // conv scratch 1,792,000
    float* P2T  = P1 + 1792000;               // 256,000
    float* XOUT = P1;                         // alias (P1 dead after conv2)
    int*   cnt  = (int*)(P2T + 256000);
    float* Sc   = P2T + 256004;               // [32,1000,1000] fp32 (starts %4==0)
    float* B0   = Sc + 32000000;              // bf16 regions begin here
    bf16* wb_qkvd = (bf16*)B0;                              // 4,194,304 bf16
    bf16* wb_f1   = (bf16*)(B0 + 2097152);
    bf16* wb_f2   = (bf16*)(B0 + 4194304);
    bf16* Erb     = (bf16*)(B0 + 6291456);                  // 256,000
    bf16* xn_b    = (bf16*)(B0 + 6419456);                  // [4000,512]
    bf16* AO_b    = (bf16*)(B0 + 7443456);
    bf16* Qb_b    = (bf16*)(B0 + 8467456);
    bf16* Kb_b    = (bf16*)(B0 + 9491456);
    bf16* Vb_b    = (bf16*)(B0 + 10515456);
    bf16* FFH_b   = (bf16*)(B0 + 11539456);                 // [4000,2048]
    bf16* Vt      = (bf16*)(B0 + 15635456);                 // [32,64,1024]
    bf16* QErB_b  = (bf16*)(B0 + 16684032);                 // [32,1000,1000]
    bf16* Pb      = (bf16*)(B0 + 32684032);                 // [32,1000,1024]
    // end: PA+2,048,000+2,048,004+32,000,000+49,068,032 = 98,964,612 fl = 396 MB

    hipMemsetAsync(cnt, 0, sizeof(int), stream);
    sniff_k<<<1024, 256, 0, stream>>>((const unsigned short*)d_in[20], 1000000, cnt);

    CvtArgs ca;
    for (int i = 0; i < 26; i++) ca.src[i] = d_in[i];
    for (int i = 0; i < 27; i++) ca.off[i] = off[i];
    ca.cnt = cnt; ca.dst = A;
    cvt_all<<<(13800576 + 255) / 256, 256, 0, stream>>>(ca);

    // downcast weights + Er to bf16 once
    f2bf_k<<<16384, 256, 0, stream>>>(qwf,  wb_qkvd, 4194304);
    f2bf_k<<<16384, 256, 0, stream>>>(f1wf, wb_f1,   4194304);
    f2bf_k<<<16384, 256, 0, stream>>>(f2wf, wb_f2,   4194304);
    f2bf_k<<<1000,  256, 0, stream>>>(Erf,  Erb,     256000);

    conv1_pool<<<dim3(4, 14, 128), 256, 0, stream>>>(spec, c1w, c1b, P1);
    conv2_pool<<<dim3(2, 64, 4), 256, 0, stream>>>(P1, c2w, c2b, P2T);
    gemm_nt<0><<<dim3(63, 8), 256, 0, stream>>>(P2T, projw, projb, nullptr, x, BT, DM, 64);

    const size_t WT = 1048576;
    for (int l = 0; l < LL; l++) {
        layernorm_k<<<BT, 256, 0, stream>>>(x, ln1g + l * DM, ln1b + l * DM, xn_b);
        mfma_nt<0, true><<<dim3(63, 4), 256, 0, stream>>>(
            xn_b, wb_qkvd + 0 * WT + (size_t)l * DM * DM, qb + l * DM, nullptr, nullptr, Qb_b, BT, DM, DM);
        mfma_nt<0, true><<<dim3(63, 4), 256, 0, stream>>>(
            xn_b, wb_qkvd + 1 * WT + (size_t)l * DM * DM, kb + l * DM, nullptr, nullptr, Kb_b, BT, DM, DM);
        mfma_nt<0, true><<<dim3(63, 4), 256, 0, stream>>>(
            xn_b, wb_qkvd + 2 * WT + (size_t)l * DM * DM, vb + l * DM, nullptr, nullptr, Vb_b, BT, DM, DM);
        vt_k<<<dim3(16, 32), 256, 0, stream>>>(Vb_b, Vt);
        qer_mfma<<<dim3(16, 8, 32), 256, 0, stream>>>(Qb_b, Erb + (size_t)l * TT * DEPTH, QErB_b);
        score_mfma<<<dim3(16, 8, 32), 256, 0, stream>>>(Qb_b, Kb_b, QErB_b, Sc);
        softmax_k<<<32000, 256, 0, stream>>>(Sc, Pb);
        pv_mfma<<<dim3(16, 1, 32), 256, 0, stream>>>(Pb, Vt, AO_b);
        mfma_nt<0, false><<<dim3(63, 4), 256, 0, stream>>>(
            AO_b, wb_qkvd + 3 * WT + (size_t)l * DM * DM, db + l * DM, x, x, nullptr, BT, DM, DM);
        layernorm_k<<<BT, 256, 0, stream>>>(x, ln2g + l * DM, ln2b + l * DM, xn_b);
        mfma_nt<1, true><<<dim3(63, 16), 256, 0, stream>>>(
            xn_b, wb_f1 + (size_t)l * FFN * DM, f1b + l * FFN, nullptr, nullptr, FFH_b, BT, FFN, DM);
        mfma_nt<0, false><<<dim3(63, 4), 256, 0, stream>>>(
            FFH_b, wb_f2 + (size_t)l * DM * FFN, f2b_ + l * DM, x, x, nullptr, BT, DM, FFN);
    }

    gemm_nt<0><<<dim3(63, 2), 256, 0, stream>>>(x, depw, depb, nullptr, XOUT, BT, EDIM, DM);
    store_out<<<2000, 256, 0, stream>>>(XOUT, cnt, d_out, BT * EDIM);
}

// Round 9
// 1809.627 us; speedup vs baseline: 7.6125x; 1.0842x over previous
//
#include <hip/hip_runtime.h>
#include <hip/hip_bf16.h>
#include <math.h>

// ---------- constants ----------
#define BB 4
#define FBINS 196
#define TT 1000
#define DM 512
#define HH 8
#define DEPTH 64
#define FFN 2048
#define LL 4
#define EDIM 128
#define BT (BB*TT)   // 4000

typedef __hip_bfloat16 bf16;
typedef __attribute__((ext_vector_type(8))) short short8;
typedef __attribute__((ext_vector_type(4))) float floatx4;

// ---------- private arena ----------
#define ARENA_BYTES 420000000ULL
static void* g_arena = nullptr;
__attribute__((constructor)) static void arena_init() {
    if (!g_arena) (void)hipMalloc(&g_arena, ARENA_BYTES);
}

__device__ __forceinline__ float gelu_f(float x) {
    return 0.5f * x * (1.0f + erff(x * 0.70710678118654752440f));
}

// ---------- dtype sniffer (cnt==0 <=> inputs are bf16) ----------
__global__ __launch_bounds__(256) void sniff_k(const unsigned short* __restrict__ p,
                                               int n, int* __restrict__ cnt) {
    int i = blockIdx.x * 256 + threadIdx.x;
    int c = 0;
    for (; i < n; i += gridDim.x * 256) {
        unsigned short u = p[i];
        if ((unsigned short)(u & 0x7FFF) > (unsigned short)0x7F80) c++;
    }
    if (c) atomicAdd(cnt, c);
}

// ---------- convert all 26 inputs into packed fp32 params ----------
struct CvtArgs {
    const void* src[26];
    unsigned off[27];
    const int* cnt;
    float* dst;
};
__global__ __launch_bounds__(256) void cvt_all(CvtArgs a) {
    unsigned i = blockIdx.x * 256 + threadIdx.x;
    if (i >= a.off[26]) return;
    bool isb = (*a.cnt == 0);
    int w = 0;
    while (i >= a.off[w + 1]) w++;
    unsigned j = i - a.off[w];
    float v = isb ? __bfloat162float(((const bf16*)a.src[w])[j])
                  : ((const float*)a.src[w])[j];
    a.dst[i] = v;
}

// ---------- fp32 -> bf16 downcast ----------
__global__ __launch_bounds__(256) void f2bf_k(const float* __restrict__ s,
                                              bf16* __restrict__ d, int n) {
    int i = blockIdx.x * 256 + threadIdx.x;
    if (i < n) d[i] = __float2bfloat16(s[i]);
}

// ---------- output store (dtype-adaptive) ----------
__global__ __launch_bounds__(256) void store_out(const float* __restrict__ xout,
                                                 const int* __restrict__ cnt,
                                                 void* __restrict__ dout, int n) {
    int i = blockIdx.x * 256 + threadIdx.x;
    if (i >= n) return;
    if (*cnt == 0) ((bf16*)dout)[i] = __float2bfloat16(xout[i]);
    else           ((float*)dout)[i] = xout[i];
}

// ---------- conv1 + gelu + maxpool(14) ----------
__global__ __launch_bounds__(256) void conv1_pool(const float* __restrict__ spec,
                                                  const float* __restrict__ w1,
                                                  const float* __restrict__ b1,
                                                  float* __restrict__ pool1) {
    __shared__ float sw[25];
    int c = blockIdx.z & 31, b = blockIdx.z >> 5;
    int p = blockIdx.y;
    int j = blockIdx.x * 256 + threadIdx.x;
    if (threadIdx.x < 25) sw[threadIdx.x] = w1[c * 25 + threadIdx.x];
    __syncthreads();
    if (j >= TT) return;
    float bias = b1[c];
    float conv[14];
#pragma unroll
    for (int i = 0; i < 14; i++) conv[i] = bias;
    const float* sp = spec + (size_t)b * FBINS * TT;
    int ibase = p * 14;
    for (int ii = ibase - 2; ii <= ibase + 15; ii++) {
        if (ii < 0 || ii >= FBINS) continue;
        float v[5];
#pragma unroll
        for (int dj = 0; dj < 5; dj++) {
            int jj = j + dj - 2;
            v[dj] = (jj >= 0 && jj < TT) ? sp[(size_t)ii * TT + jj] : 0.f;
        }
        int il = ii - ibase;
#pragma unroll
        for (int di = 0; di < 5; di++) {
            int i = il - di + 2;
            if (i >= 0 && i < 14) {
#pragma unroll
                for (int dj = 0; dj < 5; dj++) conv[i] += v[dj] * sw[di * 5 + dj];
            }
        }
    }
    float m = -1e30f;
#pragma unroll
    for (int i = 0; i < 14; i++) m = fmaxf(m, gelu_f(conv[i]));
    pool1[(((size_t)b * 32 + c) * 14 + p) * TT + j] = m;
}

// ---------- im2col for conv2: pool1 [4,32,14,1000] fp32 -> Aim [56000,800] bf16 ----
// m = (b*14+i)*1000+j ; k = ci*25+di*5+dj
__global__ __launch_bounds__(256) void im2col_k(const float* __restrict__ pool1,
                                                bf16* __restrict__ Aim) {
    int idx = blockIdx.x * 256 + threadIdx.x;       // one ushort2 (2 k) per thread
    if (idx >= 22400000) return;
    int m = idx / 400, kk = idx - m * 400;
    int b = m / 14000, r2 = m - b * 14000;
    int i = r2 / 1000, j = r2 - i * 1000;
    bf16 v[2];
#pragma unroll
    for (int e = 0; e < 2; e++) {
        int k = kk * 2 + e;
        int ci = k / 25, rm = k - ci * 25;
        int di = rm / 5, dj = rm - di * 5;
        int ii = i + di - 2, jj = j + dj - 2;
        float f = (ii >= 0 && ii < 14 && jj >= 0 && jj < TT)
                      ? pool1[(((size_t)b * 32 + ci) * 14 + ii) * TT + jj] : 0.f;
        v[e] = __float2bfloat16(f);
    }
    *(ushort2*)(Aim + (size_t)m * 800 + kk * 2) = *(ushort2*)v;
}

// ---------- conv2 epilogue: gelu + maxpool(14) + transpose ----------
// convout [56000,64] bf16 (m=(b*14+i)*1000+j) -> p2t [4000,64] bf16
__global__ __launch_bounds__(256) void pool2_k(const bf16* __restrict__ convout,
                                               bf16* __restrict__ p2t) {
    int idx = blockIdx.x * 256 + threadIdx.x;
    if (idx >= 256000) return;
    int c = idx & 63, bj = idx >> 6;
    int b = bj / 1000, j = bj - b * 1000;
    float m = -1e30f;
#pragma unroll
    for (int i = 0; i < 14; i++)
        m = fmaxf(m, gelu_f(__bfloat162float(convout[((size_t)(b * 14 + i) * 1000 + j) * 64 + c])));
    p2t[(size_t)bj * 64 + c] = __float2bfloat16(m);
}

// ---------- layernorm: fp32 in -> bf16 out ----------
__global__ __launch_bounds__(256) void layernorm_k(const float* __restrict__ x,
                                                   const float* __restrict__ g,
                                                   const float* __restrict__ bta,
                                                   bf16* __restrict__ y) {
    __shared__ float red[256];
    int row = blockIdx.x, tid = threadIdx.x;
    const float* xr = x + (size_t)row * DM;
    float v0 = xr[tid], v1 = xr[tid + 256];
    red[tid] = v0 + v1;
    __syncthreads();
    for (int s = 128; s > 0; s >>= 1) { if (tid < s) red[tid] += red[tid + s]; __syncthreads(); }
    float mu = red[0] * (1.f / 512.f);
    __syncthreads();
    float d0 = v0 - mu, d1 = v1 - mu;
    red[tid] = d0 * d0 + d1 * d1;
    __syncthreads();
    for (int s = 128; s > 0; s >>= 1) { if (tid < s) red[tid] += red[tid + s]; __syncthreads(); }
    float rstd = rsqrtf(red[0] * (1.f / 512.f) + 1e-5f);
    bf16* yr = y + (size_t)row * DM;
    yr[tid]       = __float2bfloat16(d0 * rstd * g[tid]       + bta[tid]);
    yr[tid + 256] = __float2bfloat16(d1 * rstd * g[tid + 256] + bta[tid + 256]);
}

// ---------- scalar NT GEMM (fp32), deproj only ----------
template <int ACT>
__global__ __launch_bounds__(256) void gemm_nt(const float* __restrict__ A,
                                               const float* __restrict__ B,
                                               const float* __restrict__ bias,
                                               const float* __restrict__ resid,
                                               float* __restrict__ C,
                                               int M, int N, int K) {
    __shared__ __align__(16) float As[16][68];
    __shared__ __align__(16) float Bs[16][68];
    int tid = threadIdx.x;
    int tx = tid & 15, ty = tid >> 4;
    int m0 = blockIdx.x * 64, n0 = blockIdx.y * 64;
    float c[4][4] = {};
    for (int k0 = 0; k0 < K; k0 += 16) {
#pragma unroll
        for (int i = 0; i < 4; i++) {
            int idx = i * 256 + tid;
            int kk = idx & 15, r = idx >> 4;
            int gm = m0 + r;
            As[kk][r] = (gm < M) ? A[(size_t)gm * K + k0 + kk] : 0.f;
            int gn = n0 + r;
            Bs[kk][r] = B[(size_t)gn * K + k0 + kk];
        }
        __syncthreads();
#pragma unroll
        for (int k = 0; k < 16; k++) {
            float4 av = *(const float4*)&As[k][ty * 4];
            float4 bv = *(const float4*)&Bs[k][tx * 4];
            float a[4] = {av.x, av.y, av.z, av.w};
            float bq[4] = {bv.x, bv.y, bv.z, bv.w};
#pragma unroll
            for (int i = 0; i < 4; i++)
#pragma unroll
                for (int jj = 0; jj < 4; jj++) c[i][jj] += a[i] * bq[jj];
        }
        __syncthreads();
    }
#pragma unroll
    for (int i = 0; i < 4; i++) {
        int m = m0 + ty * 4 + i;
        if (m >= M) continue;
#pragma unroll
        for (int jj = 0; jj < 4; jj++) {
            int n = n0 + tx * 4 + jj;
            float v = c[i][jj] + bias[n];
            if (resid) v += resid[(size_t)m * N + n];
            if (ACT == 1) v = fmaxf(v, 0.f);
            C[(size_t)m * N + n] = v;
        }
    }
}

// ---------- unified MFMA bf16 NT GEMM, 128(M) x NT(N) tile ----------
// NT=128: wave w covers n-slice w*32, all 128 m (8x2 accs).
// NT=64 : wave w covers m-slice (w>>1)*64, n-slice (w&1)*32 (4x2 accs).
// ROUTE=1 (QKV fused): B rows route over tensors of 512 rows with stride
// wstride (weights), bstride (bias), ostride (output, bf16 elems).
template <int NT, int ROUTE, int ACT, bool OUT_BF16>
__global__ __launch_bounds__(256) void mfma_big(const bf16* __restrict__ A,
                                                const bf16* __restrict__ B,
                                                const float* __restrict__ bias,
                                                const float* __restrict__ resid,
                                                float* __restrict__ Cf,
                                                bf16* __restrict__ Cb,
                                                int M, int N, int K,
                                                size_t wstride, int bstride,
                                                size_t ostride) {
    __shared__ __align__(16) short Asm[128 * 40];
    __shared__ __align__(16) short Bsm[NT * 40];
    int tid = threadIdx.x, wave = tid >> 6, lane = tid & 63;
    int q = lane >> 4, l15 = lane & 15;
    int m0 = blockIdx.x * 128, n0 = blockIdx.y * NT;
    int lrow = tid >> 2, lk = (tid & 3) * 8;
    constexpr int MF = (NT == 128) ? 8 : 4;
    int m0w = (NT == 128) ? 0 : ((wave >> 1) * 64);
    int nfb = (NT == 128) ? (wave * 32) : ((wave & 1) * 32);
    floatx4 acc[MF][2] = {};
    for (int k0 = 0; k0 < K; k0 += 32) {
#pragma unroll
        for (int hh = 0; hh < 2; hh++) {      // stage A: 128 rows
            int row = lrow + hh * 64, gm = m0 + row;
            uint4 v = make_uint4(0u, 0u, 0u, 0u);
            if (gm < M) v = *(const uint4*)(A + (size_t)gm * K + k0 + lk);
            *(uint4*)(Asm + row * 40 + lk) = v;
        }
        if (NT == 128) {
#pragma unroll
            for (int hh = 0; hh < 2; hh++) {
                int row = lrow + hh * 64, gn = n0 + row;
                const bf16* src = ROUTE
                    ? B + (size_t)(gn >> 9) * wstride + (size_t)(gn & 511) * K + k0 + lk
                    : B + (size_t)gn * K + k0 + lk;
                *(uint4*)(Bsm + row * 40 + lk) = *(const uint4*)src;
            }
        } else {
            int gn = n0 + lrow;
            *(uint4*)(Bsm + lrow * 40 + lk) =
                *(const uint4*)(B + (size_t)gn * K + k0 + lk);
        }
        __syncthreads();
        short8 a[MF], b2[2];
#pragma unroll
        for (int im = 0; im < MF; im++)
            a[im] = *(const short8*)(Asm + (m0w + im * 16 + l15) * 40 + q * 8);
#pragma unroll
        for (int jn = 0; jn < 2; jn++)
            b2[jn] = *(const short8*)(Bsm + (nfb + jn * 16 + l15) * 40 + q * 8);
#pragma unroll
        for (int im = 0; im < MF; im++)
#pragma unroll
            for (int jn = 0; jn < 2; jn++)
                acc[im][jn] = __builtin_amdgcn_mfma_f32_16x16x32_bf16(
                    a[im], b2[jn], acc[im][jn], 0, 0, 0);
        __syncthreads();
    }
#pragma unroll
    for (int im = 0; im < MF; im++) {
#pragma unroll
        for (int jn = 0; jn < 2; jn++) {
            int nn = n0 + nfb + jn * 16 + l15;
            float bval = ROUTE ? bias[(nn >> 9) * bstride + (nn & 511)] : bias[nn];
#pragma unroll
            for (int r = 0; r < 4; r++) {
                int m = m0 + m0w + im * 16 + q * 4 + r;
                if (m >= M) continue;
                float v = acc[im][jn][r] + bval;
                if (resid) v += resid[(size_t)m * N + nn];
                if (ACT == 1) v = fmaxf(v, 0.f);
                if (ROUTE)
                    Cb[(size_t)(nn >> 9) * ostride + (size_t)m * 512 + (nn & 511)] =
                        __float2bfloat16(v);
                else if (OUT_BF16)
                    Cb[(size_t)m * N + nn] = __float2bfloat16(v);
                else
                    Cf[(size_t)m * N + nn] = v;
            }
        }
    }
}

// ---------- V transpose: Vb[b,t,h*64+d] -> Vt[z][d][t] (stride 1024, zero-pad) ----
__global__ __launch_bounds__(256) void vt_k(const bf16* __restrict__ Vb,
                                            bf16* __restrict__ Vt) {
    __shared__ short tile[64][65];
    int t0 = blockIdx.x * 64, z = blockIdx.y;
    int b = z >> 3, h = z & 7;
    int tid = threadIdx.x;
#pragma unroll
    for (int i = 0; i < 16; i++) {
        int tr = i * 4 + (tid >> 6), d = tid & 63;
        int t = t0 + tr;
        bf16 v = (t < TT) ? Vb[((size_t)b * TT + t) * DM + h * 64 + d] : (bf16)__float2bfloat16(0.f);
        tile[tr][d] = *(short*)&v;
    }
    __syncthreads();
#pragma unroll
    for (int i = 0; i < 16; i++) {
        int dr = i * 4 + (tid >> 6), tc = tid & 63;
        *(short*)&Vt[(size_t)z * 65536 + dr * 1024 + t0 + tc] = tile[tc][dr];
    }
}

// ---------- qer MFMA: QErB_b[z,s,r] = Q[z][s,:].Er[r,:]  grid (16,8,32) ----------
__global__ __launch_bounds__(256) void qer_mfma(const bf16* __restrict__ Q,
                                                const bf16* __restrict__ Er,
                                                bf16* __restrict__ QErB) {
    __shared__ __align__(16) short Asm[64 * 40];
    __shared__ __align__(16) short Bsm[128 * 40];
    int tid = threadIdx.x;
    int wave = tid >> 6, lane = tid & 63;
    int q = lane >> 4, l15 = lane & 15;
    int m0 = blockIdx.x * 64, n0 = blockIdx.y * 128;
    int z = blockIdx.z, b = z >> 3, h = z & 7;
    const bf16* Ap = Q + (size_t)b * TT * DM + h * 64;
    int lrow = tid >> 2, lk = (tid & 3) * 8;
    floatx4 acc[4][2] = {};
    for (int k0 = 0; k0 < 64; k0 += 32) {
        {
            int gm = m0 + lrow;
            uint4 v = make_uint4(0u, 0u, 0u, 0u);
            if (gm < TT) v = *(const uint4*)(Ap + (size_t)gm * DM + k0 + lk);
            *(uint4*)(Asm + lrow * 40 + lk) = v;
        }
        {
            int gn = n0 + lrow;
            uint4 v0 = make_uint4(0u, 0u, 0u, 0u), v1 = v0;
            if (gn < TT)      v0 = *(const uint4*)(Er + (size_t)gn * 64 + k0 + lk);
            if (gn + 64 < TT) v1 = *(const uint4*)(Er + (size_t)(gn + 64) * 64 + k0 + lk);
            *(uint4*)(Bsm + lrow * 40 + lk) = v0;
            *(uint4*)(Bsm + (lrow + 64) * 40 + lk) = v1;
        }
        __syncthreads();
        short8 a[4], bf[2];
#pragma unroll
        for (int im = 0; im < 4; im++)
            a[im] = *(const short8*)(Asm + (im * 16 + l15) * 40 + q * 8);
#pragma unroll
        for (int jn = 0; jn < 2; jn++)
            bf[jn] = *(const short8*)(Bsm + (wave * 32 + jn * 16 + l15) * 40 + q * 8);
#pragma unroll
        for (int im = 0; im < 4; im++)
#pragma unroll
            for (int jn = 0; jn < 2; jn++)
                acc[im][jn] = __builtin_amdgcn_mfma_f32_16x16x32_bf16(
                    a[im], bf[jn], acc[im][jn], 0, 0, 0);
        __syncthreads();
    }
    bf16* Cz = QErB + (size_t)z * 1000000;
#pragma unroll
    for (int im = 0; im < 4; im++) {
#pragma unroll
        for (int jn = 0; jn < 2; jn++) {
            int n = n0 + wave * 32 + jn * 16 + l15;
            if (n >= TT) continue;
#pragma unroll
            for (int r = 0; r < 4; r++) {
                int m = m0 + im * 16 + q * 4 + r;
                if (m < TT) Cz[(size_t)m * TT + n] = __float2bfloat16(acc[im][jn][r]);
            }
        }
    }
}

// ---------- score MFMA + skew epilogue: Sc = (Q.K^T + Srel)*0.125  grid (16,8,32) --
__global__ __launch_bounds__(256) void score_mfma(const bf16* __restrict__ Q,
                                                  const bf16* __restrict__ K,
                                                  const bf16* __restrict__ QErB,
                                                  float* __restrict__ Sc) {
    __shared__ __align__(16) short Asm[64 * 40];
    __shared__ __align__(16) short Bsm[128 * 40];
    int tid = threadIdx.x;
    int wave = tid >> 6, lane = tid & 63;
    int q = lane >> 4, l15 = lane & 15;
    int m0 = blockIdx.x * 64, n0 = blockIdx.y * 128;
    int z = blockIdx.z, b = z >> 3, h = z & 7;
    const bf16* Ap = Q + (size_t)b * TT * DM + h * 64;
    const bf16* Bp = K + (size_t)b * TT * DM + h * 64;
    int lrow = tid >> 2, lk = (tid & 3) * 8;
    floatx4 acc[4][2] = {};
    for (int k0 = 0; k0 < 64; k0 += 32) {
        {
            int gm = m0 + lrow;
            uint4 v = make_uint4(0u, 0u, 0u, 0u);
            if (gm < TT) v = *(const uint4*)(Ap + (size_t)gm * DM + k0 + lk);
            *(uint4*)(Asm + lrow * 40 + lk) = v;
        }
        {
            int gn = n0 + lrow;
            uint4 v0 = make_uint4(0u, 0u, 0u, 0u), v1 = v0;
            if (gn < TT)      v0 = *(const uint4*)(Bp + (size_t)gn * DM + k0 + lk);
            if (gn + 64 < TT) v1 = *(const uint4*)(Bp + (size_t)(gn + 64) * DM + k0 + lk);
            *(uint4*)(Bsm + lrow * 40 + lk) = v0;
            *(uint4*)(Bsm + (lrow + 64) * 40 + lk) = v1;
        }
        __syncthreads();
        short8 a[4], bf[2];
#pragma unroll
        for (int im = 0; im < 4; im++)
            a[im] = *(const short8*)(Asm + (im * 16 + l15) * 40 + q * 8);
#pragma unroll
        for (int jn = 0; jn < 2; jn++)
            bf[jn] = *(const short8*)(Bsm + (wave * 32 + jn * 16 + l15) * 40 + q * 8);
#pragma unroll
        for (int im = 0; im < 4; im++)
#pragma unroll
            for (int jn = 0; jn < 2; jn++)
                acc[im][jn] = __builtin_amdgcn_mfma_f32_16x16x32_bf16(
                    a[im], bf[jn], acc[im][jn], 0, 0, 0);
        __syncthreads();
    }
    const bf16* Ez = QErB + (size_t)z * 1000000;
    float* Cz = Sc + (size_t)z * 1000000;
#pragma unroll
    for (int im = 0; im < 4; im++) {
#pragma unroll
        for (int jn = 0; jn < 2; jn++) {
            int n = n0 + wave * 32 + jn * 16 + l15;   // t
            if (n >= TT) continue;
#pragma unroll
            for (int r = 0; r < 4; r++) {
                int m = m0 + im * 16 + q * 4 + r;     // s
                if (m >= TT) continue;
                float rel;
                if (n == m + 1)  rel = 0.f;
                else if (n <= m) rel = __bfloat162float(Ez[(size_t)m * TT + (TT - 1 - m + n)]);
                else             rel = __bfloat162float(Ez[(size_t)(m + 1) * TT + (n - m - 2)]);
                Cz[(size_t)m * TT + n] = (acc[im][jn][r] + rel) * 0.125f;
            }
        }
    }
}

// ---------- softmax: Sc fp32 (stride 1000) -> Pb bf16 (stride 1024, zero-padded) ----
__global__ __launch_bounds__(256) void softmax_k(const float* __restrict__ Sc,
                                                 bf16* __restrict__ Pb) {
    __shared__ float red[256];
    const float* row = Sc + (size_t)blockIdx.x * TT;
    bf16* prow = Pb + (size_t)blockIdx.x * 1024;
    int tid = threadIdx.x;
    float v[4]; float lm = -1e30f;
#pragma unroll
    for (int i = 0; i < 4; i++) {
        int t = tid + i * 256;
        v[i] = (t < TT) ? row[t] : -1e30f;
        lm = fmaxf(lm, v[i]);
    }
    red[tid] = lm; __syncthreads();
    for (int s = 128; s > 0; s >>= 1) { if (tid < s) red[tid] = fmaxf(red[tid], red[tid + s]); __syncthreads(); }
    float mx = red[0]; __syncthreads();
    float ls = 0.f;
#pragma unroll
    for (int i = 0; i < 4; i++) {
        int t = tid + i * 256;
        v[i] = (t < TT) ? __expf(v[i] - mx) : 0.f;
        ls += v[i];
    }
    red[tid] = ls; __syncthreads();
    for (int s = 128; s > 0; s >>= 1) { if (tid < s) red[tid] += red[tid + s]; __syncthreads(); }
    float inv = 1.f / red[0]; __syncthreads();
#pragma unroll
    for (int i = 0; i < 4; i++) {
        int t = tid + i * 256;
        prow[t] = __float2bfloat16(v[i] * inv);
    }
}

// ---------- pv MFMA: AO[b,s,h*64+d] = P[z] @ Vt[z]^T   grid (16,1,32) ----------
__global__ __launch_bounds__(256) void pv_mfma(const bf16* __restrict__ P,
                                               const bf16* __restrict__ Vt,
                                               bf16* __restrict__ AO) {
    __shared__ __align__(16) short Asm[64 * 40];
    __shared__ __align__(16) short Bsm[64 * 40];
    int tid = threadIdx.x;
    int wave = tid >> 6, lane = tid & 63;
    int q = lane >> 4, l15 = lane & 15;
    int m0 = blockIdx.x * 64;
    int z = blockIdx.z, b = z >> 3, h = z & 7;
    const bf16* Ap = P + (size_t)z * 1024000;
    const bf16* Bp = Vt + (size_t)z * 65536;
    int lrow = tid >> 2, lk = (tid & 3) * 8;
    floatx4 acc[4] = {};
    for (int k0 = 0; k0 < 1024; k0 += 32) {
        {
            int gm = m0 + lrow;
            uint4 v = make_uint4(0u, 0u, 0u, 0u);
            if (gm < TT) v = *(const uint4*)(Ap + (size_t)gm * 1024 + k0 + lk);
            *(uint4*)(Asm + lrow * 40 + lk) = v;
        }
        *(uint4*)(Bsm + lrow * 40 + lk) =
            *(const uint4*)(Bp + (size_t)lrow * 1024 + k0 + lk);
        __syncthreads();
        short8 a = *(const short8*)(Asm + (wave * 16 + l15) * 40 + q * 8);
#pragma unroll
        for (int jn = 0; jn < 4; jn++) {
            short8 bf = *(const short8*)(Bsm + (jn * 16 + l15) * 40 + q * 8);
            acc[jn] = __builtin_amdgcn_mfma_f32_16x16x32_bf16(a, bf, acc[jn], 0, 0, 0);
        }
        __syncthreads();
    }
#pragma unroll
    for (int jn = 0; jn < 4; jn++) {
        int n = jn * 16 + l15;  // d
#pragma unroll
        for (int r = 0; r < 4; r++) {
            int m = m0 + wave * 16 + q * 4 + r;   // s
            if (m < TT)
                AO[((size_t)b * TT + m) * DM + h * 64 + n] = __float2bfloat16(acc[jn][r]);
        }
    }
}

// ---------- launch ----------
extern "C" void kernel_launch(void* const* d_in, const int* in_sizes, int n_in,
                              void* d_out, int out_size, void* d_ws, size_t ws_size,
                              hipStream_t stream) {
    if (!g_arena) (void)hipMalloc(&g_arena, ARENA_BYTES);
    float* A = (float*)g_arena;

    static const unsigned off[27] = {
        0, 784000, 784800, 784832, 836032, 836096, 868864, 869376, 871424,
        873472, 1922048, 2970624, 4019200, 5067776, 5069824, 5071872,
        5073920, 5075968, 5331968, 5334016, 5336064, 9530368, 9538560,
        13732864, 13734912, 13800448, 13800576};
    const float* spec  = A + off[0];
    const float* c1w   = A + off[1];
    const float* c1b   = A + off[2];
    const float* c2wf  = A + off[3];
    const float* c2b   = A + off[4];
    const float* projwf= A + off[5];
    const float* projb = A + off[6];
    const float* ln1g  = A + off[7];
    const float* ln1b  = A + off[8];
    const float* qwf   = A + off[9];   // qw|kw|vw|dw contiguous
    const float* qb    = A + off[13];
    const float* db    = A + off[16];
    const float* Erf   = A + off[17];
    const float* ln2g  = A + off[18];
    const float* ln2b  = A + off[19];
    const float* f1wf  = A + off[20];
    const float* f1b   = A + off[21];
    const float* f2wf  = A + off[22];
    const float* f2b_  = A + off[23];
    const float* depw  = A + off[24];
    const float* depb  = A + off[25];

    // ---- arena layout (float offsets; bf16 starts %4==0 -> 16B aligned) ----
    const size_t PA = 13800576;
    float* x    = A + PA;                     // [4000,512] fp32
    float* P1   = x + 2048000;                // conv scratch 1,792,000 fl
    float* SM   = P1 + 1792000;               // small region 256,000 fl
    bf16* p2t_b   = (bf16*)SM;                // 256,000 bf16 = 128,000 fl
    bf16* projw_b = (bf16*)(SM + 128000);     // 32,768 bf16
    bf16* w2b     = (bf16*)(SM + 150000);     // 51,200 bf16
    float* XOUT = P1;                         // alias (P1 dead after conv path)
    int*   cnt  = (int*)(SM + 256000);
    float* Sc   = SM + 256004;                // [32,1000,1000] fp32
    bf16* Aim   = (bf16*)Sc;                  // pre-loop alias: [56000,800] bf16
    float* B0   = Sc + 32000000;
    bf16* wb_qkvd = (bf16*)B0;                              // 4,194,304 bf16
    bf16* wb_f1   = (bf16*)(B0 + 2097152);
    bf16* wb_f2   = (bf16*)(B0 + 4194304);
    bf16* Erb     = (bf16*)(B0 + 6291456);                  // 256,000
    bf16* xn_b    = (bf16*)(B0 + 6419456);                  // [4000,512]
    bf16* AO_b    = (bf16*)(B0 + 7443456);
    bf16* Qb_b    = (bf16*)(B0 + 8467456);
    bf16* Kb_b    = (bf16*)(B0 + 9491456);
    bf16* Vb_b    = (bf16*)(B0 + 10515456);
    bf16* FFH_b   = (bf16*)(B0 + 11539456);                 // [4000,2048]
    bf16* Vt      = (bf16*)(B0 + 15635456);                 // [32,64,1024]
    bf16* QErB_b  = (bf16*)(B0 + 16684032);                 // [32,1000,1000]
    bf16* convout = QErB_b;                   // pre-loop alias: [56000,64] bf16
    bf16* Pb      = (bf16*)(B0 + 32684032);                 // [32,1000,1024]

    hipMemsetAsync(cnt, 0, sizeof(int), stream);
    sniff_k<<<1024, 256, 0, stream>>>((const unsigned short*)d_in[20], 1000000, cnt);

    CvtArgs ca;
    for (int i = 0; i < 26; i++) ca.src[i] = d_in[i];
    for (int i = 0; i < 27; i++) ca.off[i] = off[i];
    ca.cnt = cnt; ca.dst = A;
    cvt_all<<<(13800576 + 255) / 256, 256, 0, stream>>>(ca);

    // downcast weights to bf16 once
    f2bf_k<<<16384, 256, 0, stream>>>(qwf,   wb_qkvd, 4194304);
    f2bf_k<<<16384, 256, 0, stream>>>(f1wf,  wb_f1,   4194304);
    f2bf_k<<<16384, 256, 0, stream>>>(f2wf,  wb_f2,   4194304);
    f2bf_k<<<1000,  256, 0, stream>>>(Erf,   Erb,     256000);
    f2bf_k<<<128,   256, 0, stream>>>(projwf, projw_b, 32768);
    f2bf_k<<<200,   256, 0, stream>>>(c2wf,  w2b,     51200);

    // conv frontend
    conv1_pool<<<dim3(4, 14, 128), 256, 0, stream>>>(spec, c1w, c1b, P1);
    im2col_k<<<87500, 256, 0, stream>>>(P1, Aim);
    mfma_big<64, 0, 0, true><<<dim3(438, 1), 256, 0, stream>>>(
        Aim, w2b, c2b, nullptr, nullptr, convout, 56000, 64, 800, 0, 0, 0);
    pool2_k<<<1000, 256, 0, stream>>>(convout, p2t_b);
    mfma_big<64, 0, 0, false><<<dim3(32, 8), 256, 0, stream>>>(
        p2t_b, projw_b, projb, nullptr, x, nullptr, BT, DM, 64, 0, 0, 0);

    for (int l = 0; l < LL; l++) {
        layernorm_k<<<BT, 256, 0, stream>>>(x, ln1g + l * DM, ln1b + l * DM, xn_b);
        // fused QKV: N=1536, routed over qw/kw/vw blocks
        mfma_big<128, 1, 0, true><<<dim3(32, 12), 256, 0, stream>>>(
            xn_b, wb_qkvd + (size_t)l * DM * DM, qb + l * DM, nullptr,
            nullptr, Qb_b, BT, 1536, DM, 1048576, 2048, 2048000);
        vt_k<<<dim3(16, 32), 256, 0, stream>>>(Vb_b, Vt);
        qer_mfma<<<dim3(16, 8, 32), 256, 0, stream>>>(Qb_b, Erb + (size_t)l * TT * DEPTH, QErB_b);
        score_mfma<<<dim3(16, 8, 32), 256, 0, stream>>>(Qb_b, Kb_b, QErB_b, Sc);
        softmax_k<<<32000, 256, 0, stream>>>(Sc, Pb);
        pv_mfma<<<dim3(16, 1, 32), 256, 0, stream>>>(Pb, Vt, AO_b);
        mfma_big<64, 0, 0, false><<<dim3(32, 8), 256, 0, stream>>>(
            AO_b, wb_qkvd + 3 * 1048576 + (size_t)l * DM * DM, db + l * DM, x,
            x, nullptr, BT, DM, DM, 0, 0, 0);
        layernorm_k<<<BT, 256, 0, stream>>>(x, ln2g + l * DM, ln2b + l * DM, xn_b);
        mfma_big<128, 0, 1, true><<<dim3(32, 16), 256, 0, stream>>>(
            xn_b, wb_f1 + (size_t)l * FFN * DM, f1b + l * FFN, nullptr,
            nullptr, FFH_b, BT, FFN, DM, 0, 0, 0);
        mfma_big<64, 0, 0, false><<<dim3(32, 8), 256, 0, stream>>>(
            FFH_b, wb_f2 + (size_t)l * DM * FFN, f2b_ + l * DM, x,
            x, nullptr, BT, DM, FFN, 0, 0, 0);
    }

    gemm_nt<0><<<dim3(63, 2), 256, 0, stream>>>(x, depw, depb, nullptr, XOUT, BT, EDIM, DM);
    store_out<<<2000, 256, 0, stream>>>(XOUT, cnt, d_out, BT * EDIM);
}